// Round 1
// baseline (832.268 us; speedup 1.0000x reference)
//
#include <hip/hip_runtime.h>
#include <hip/hip_bf16.h>
#include <math.h>

#define HID 128

static inline size_t align256(size_t x){ return (x + 255) & ~(size_t)255; }

// ---------------- GEMM: C = act(A@W + b [+ add]) ----------------
// A:[n,128] W:[128,128] bias:[128] C:[n,128]; 64x64 tile, K staged in 2 chunks of 64.
__global__ __launch_bounds__(256) void k_gemm(
    const float* __restrict__ A, const float* __restrict__ W,
    const float* __restrict__ bias, const float* __restrict__ addsrc,
    float* __restrict__ C, int nrows, int dorelu)
{
  __shared__ float At[64][65];   // [k][row], padded
  __shared__ float Wt[64][66];   // [k][col], padded
  const int tid = threadIdx.x;
  const int rb = blockIdx.x * 64;
  const int cb = blockIdx.y * 64;
  const int tx = tid & 15, ty = tid >> 4;
  float acc[4][4] = {};
  for (int c = 0; c < 2; ++c) {
    int flat = tid;
    #pragma unroll
    for (int it = 0; it < 4; ++it, flat += 256) {
      int row = flat >> 4, kq = flat & 15;
      int gr = rb + row;
      float4 a = make_float4(0.f, 0.f, 0.f, 0.f);
      if (gr < nrows) a = *reinterpret_cast<const float4*>(A + (size_t)gr * HID + c * 64 + kq * 4);
      At[kq*4+0][row] = a.x; At[kq*4+1][row] = a.y;
      At[kq*4+2][row] = a.z; At[kq*4+3][row] = a.w;
    }
    flat = tid;
    #pragma unroll
    for (int it = 0; it < 4; ++it, flat += 256) {
      int k = flat >> 4, cq = flat & 15;
      float4 w = *reinterpret_cast<const float4*>(W + (size_t)(c*64 + k) * HID + cb + cq * 4);
      *reinterpret_cast<float4*>(&Wt[k][cq*4]) = w;
    }
    __syncthreads();
    for (int kk = 0; kk < 64; ++kk) {
      float4 a4 = *reinterpret_cast<const float4*>(&At[kk][ty*4]);
      float4 w4 = *reinterpret_cast<const float4*>(&Wt[kk][tx*4]);
      float a[4] = {a4.x, a4.y, a4.z, a4.w};
      float w[4] = {w4.x, w4.y, w4.z, w4.w};
      #pragma unroll
      for (int i = 0; i < 4; ++i)
        #pragma unroll
        for (int j = 0; j < 4; ++j)
          acc[i][j] = fmaf(a[i], w[j], acc[i][j]);
    }
    __syncthreads();
  }
  float b4[4];
  *reinterpret_cast<float4*>(b4) = *reinterpret_cast<const float4*>(bias + cb + tx*4);
  #pragma unroll
  for (int i = 0; i < 4; ++i) {
    int gr = rb + ty*4 + i;
    if (gr >= nrows) break;
    float r[4];
    #pragma unroll
    for (int j = 0; j < 4; ++j) r[j] = acc[i][j] + b4[j];
    if (addsrc) {
      float4 ad = *reinterpret_cast<const float4*>(addsrc + (size_t)gr * HID + cb + tx*4);
      r[0] += ad.x; r[1] += ad.y; r[2] += ad.z; r[3] += ad.w;
    }
    if (dorelu) {
      r[0] = fmaxf(r[0], 0.f); r[1] = fmaxf(r[1], 0.f);
      r[2] = fmaxf(r[2], 0.f); r[3] = fmaxf(r[3], 0.f);
    }
    *reinterpret_cast<float4*>(C + (size_t)gr * HID + cb + tx*4) =
        make_float4(r[0], r[1], r[2], r[3]);
  }
}

// ---------------- CSR build ----------------
__global__ void k_hist(const int* __restrict__ dst, int* __restrict__ deg, int e) {
  for (int i = blockIdx.x * blockDim.x + threadIdx.x; i < e; i += gridDim.x * blockDim.x)
    atomicAdd(&deg[dst[i]], 1);
}

__global__ void k_scan_a(const int* __restrict__ deg, int* __restrict__ rowptr,
                         int* __restrict__ bsum, int n) {
  __shared__ int tmp[512];
  int t = threadIdx.x, i = blockIdx.x * 512 + t;
  int v = (i < n) ? deg[i] : 0;
  tmp[t] = v;
  __syncthreads();
  for (int off = 1; off < 512; off <<= 1) {
    int u = (t >= off) ? tmp[t - off] : 0;
    __syncthreads();
    tmp[t] += u;
    __syncthreads();
  }
  if (i < n) rowptr[i] = tmp[t] - v;       // exclusive
  if (t == 511) bsum[blockIdx.x] = tmp[t]; // block total
}

__global__ void k_scan_b(int* bsum, int nb) {
  if (threadIdx.x == 0 && blockIdx.x == 0) {
    int acc = 0;
    for (int i = 0; i < nb; ++i) { int v = bsum[i]; bsum[i] = acc; acc += v; }
  }
}

__global__ void k_scan_c(int* __restrict__ rowptr, int* __restrict__ cursor,
                         const int* __restrict__ bsum, int n, int e) {
  int i = blockIdx.x * 512 + threadIdx.x;
  if (i < n) { int v = rowptr[i] + bsum[blockIdx.x]; rowptr[i] = v; cursor[i] = v; }
  if (i == 0) rowptr[n] = e;
}

__global__ void k_scatter(const int* __restrict__ srcA, const int* __restrict__ dstA,
                          int* __restrict__ cursor, int* __restrict__ csrc, int e) {
  for (int i = blockIdx.x * blockDim.x + threadIdx.x; i < e; i += gridDim.x * blockDim.x) {
    int pos = atomicAdd(&cursor[dstA[i]], 1);
    csrc[pos] = srcA[i];
  }
}

// ---------------- fused node attention (flash-style online softmax) ----------------
// one wave per node; lane l holds feature slots l and 64+l (4 heads x 32 dims = 128)
__global__ __launch_bounds__(256) void k_attn(
    const float* __restrict__ Q, const float* __restrict__ K, const float* __restrict__ V,
    const int* __restrict__ rowptr, const int* __restrict__ csrc,
    float* __restrict__ AGG, int n)
{
  int wid = blockIdx.x * 4 + (threadIdx.x >> 6);
  if (wid >= n) return;
  int lane = threadIdx.x & 63;
  const float* qp = Q + (size_t)wid * HID;
  float q0 = qp[lane], q1 = qp[64 + lane];
  int e0 = rowptr[wid], e1 = rowptr[wid + 1];
  float m0 = -INFINITY, m1 = -INFINITY, s0 = 0.f, s1 = 0.f, a0 = 0.f, a1 = 0.f;
  const float sc = 0.17677669529663687f;  // 1/sqrt(32)
  for (int j = e0; j < e1; ++j) {
    int src = csrc[j];
    const float* kp = K + (size_t)src * HID;
    const float* vp = V + (size_t)src * HID;
    float k0 = kp[lane], k1 = kp[64 + lane];
    float v0 = vp[lane], v1 = vp[64 + lane];
    float d0 = q0 * k0, d1 = q1 * k1;
    #pragma unroll
    for (int off = 16; off >= 1; off >>= 1) {  // reduce within 32-lane halves (one head each)
      d0 += __shfl_xor(d0, off);
      d1 += __shfl_xor(d1, off);
    }
    float l0 = d0 * sc, l1 = d1 * sc;
    float nm0 = fmaxf(m0, l0), nm1 = fmaxf(m1, l1);
    float c0 = __expf(m0 - nm0), c1 = __expf(m1 - nm1);
    float p0 = __expf(l0 - nm0), p1 = __expf(l1 - nm1);
    s0 = s0 * c0 + p0;       s1 = s1 * c1 + p1;
    a0 = a0 * c0 + p0 * v0;  a1 = a1 * c1 + p1 * v1;
    m0 = nm0; m1 = nm1;
  }
  float r0 = (s0 > 0.f) ? a0 / s0 : 0.f;
  float r1 = (s1 > 0.f) ? a1 / s1 : 0.f;
  AGG[(size_t)wid * HID + lane] = r0;
  AGG[(size_t)wid * HID + 64 + lane] = r1;
}

// ---------------- pooling (batch is sorted) ----------------
__global__ void k_pool(const float* __restrict__ Hin, const int* __restrict__ batch,
                       float* __restrict__ psum, float* __restrict__ pcnt, int n) {
  int t = threadIdx.x;  // 128 threads, one per column
  int chunk = (n + gridDim.x - 1) / gridDim.x;
  int n0 = blockIdx.x * chunk, n1 = min(n, n0 + chunk);
  if (n0 >= n1) return;
  int curg = batch[n0];
  float acc = 0.f; int c = 0;
  for (int i = n0; i < n1; ++i) {
    int g = batch[i];
    if (g != curg) {
      atomicAdd(&psum[curg * HID + t], acc);
      if (t == 0) atomicAdd(&pcnt[curg], (float)c);
      acc = 0.f; c = 0; curg = g;
    }
    acc += Hin[(size_t)i * HID + t]; ++c;
  }
  atomicAdd(&psum[curg * HID + t], acc);
  if (t == 0) atomicAdd(&pcnt[curg], (float)c);
}

__global__ void k_fc(const float* __restrict__ psum, const float* __restrict__ pcnt,
                     const float* __restrict__ Wfc, const float* __restrict__ bfc,
                     float* __restrict__ out) {
  __shared__ float red[2];
  int g = blockIdx.x, t = threadIdx.x;  // 128 threads
  float v = psum[g * HID + t] * Wfc[t];
  #pragma unroll
  for (int off = 32; off >= 1; off >>= 1) v += __shfl_xor(v, off);
  if ((t & 63) == 0) red[t >> 6] = v;
  __syncthreads();
  if (t == 0) out[g] = (red[0] + red[1]) / fmaxf(pcnt[g], 1.f) + bfc[0];
}

extern "C" void kernel_launch(void* const* d_in, const int* in_sizes, int n_in,
                              void* d_out, int out_size, void* d_ws, size_t ws_size,
                              hipStream_t stream)
{
  const float* x   = (const float*)d_in[0];
  const int*   ei  = (const int*)d_in[1];
  const int*   bat = (const int*)d_in[2];
  const float *Wq1 = (const float*)d_in[3],  *bq1 = (const float*)d_in[4];
  const float *Wk1 = (const float*)d_in[5],  *bk1 = (const float*)d_in[6];
  const float *Wv1 = (const float*)d_in[7],  *bv1 = (const float*)d_in[8];
  const float *Ws1 = (const float*)d_in[9],  *bs1 = (const float*)d_in[10];
  const float *Wq2 = (const float*)d_in[11], *bq2 = (const float*)d_in[12];
  const float *Wk2 = (const float*)d_in[13], *bk2 = (const float*)d_in[14];
  const float *Wv2 = (const float*)d_in[15], *bv2 = (const float*)d_in[16];
  const float *Ws2 = (const float*)d_in[17], *bs2 = (const float*)d_in[18];
  const float *Wfc = (const float*)d_in[19], *bfc = (const float*)d_in[20];
  float* out = (float*)d_out;

  const int N = in_sizes[0] / HID;
  const int E = in_sizes[1] / 2;
  const int G = 64;

  char* p = (char*)d_ws;
  size_t NF = (size_t)N * HID * sizeof(float);
  auto alloc = [&](size_t bytes) -> char* { char* r = p; p += align256(bytes); return r; };
  float* Qb = (float*)alloc(NF);
  float* Kb = (float*)alloc(NF);
  float* Vb = (float*)alloc(NF);
  float* Ab = (float*)alloc(NF);   // attention aggregate
  float* Hb = (float*)alloc(NF);   // layer-1 output
  int* rowptr = (int*)alloc((size_t)(N + 1) * sizeof(int));
  int* cursor = (int*)alloc((size_t)N * sizeof(int));
  int* deg    = (int*)alloc((size_t)N * sizeof(int));
  int* bsum   = (int*)alloc(4096);
  int* csrc   = (int*)alloc((size_t)E * sizeof(int));
  float* psum = (float*)alloc((size_t)G * HID * sizeof(float));
  float* pcnt = (float*)alloc((size_t)G * sizeof(float));

  const int* esrc = ei;       // edge_index[0] = src
  const int* edst = ei + E;   // edge_index[1] = dst

  hipMemsetAsync(deg, 0, (size_t)N * sizeof(int), stream);
  hipMemsetAsync(psum, 0, (size_t)G * HID * sizeof(float), stream);
  hipMemsetAsync(pcnt, 0, (size_t)G * sizeof(float), stream);

  // CSR by dst (edge_index is constant across layers)
  k_hist<<<512, 256, 0, stream>>>(edst, deg, E);
  int SB = (N + 511) / 512;
  k_scan_a<<<SB, 512, 0, stream>>>(deg, rowptr, bsum, N);
  k_scan_b<<<1, 1, 0, stream>>>(bsum, SB);
  k_scan_c<<<SB, 512, 0, stream>>>(rowptr, cursor, bsum, N, E);
  k_scatter<<<512, 256, 0, stream>>>(esrc, edst, cursor, csrc, E);

  dim3 ggrid((N + 63) / 64, 2);
  // layer 1
  k_gemm<<<ggrid, 256, 0, stream>>>(x, Wq1, bq1, nullptr, Qb, N, 0);
  k_gemm<<<ggrid, 256, 0, stream>>>(x, Wk1, bk1, nullptr, Kb, N, 0);
  k_gemm<<<ggrid, 256, 0, stream>>>(x, Wv1, bv1, nullptr, Vb, N, 0);
  k_attn<<<(N + 3) / 4, 256, 0, stream>>>(Qb, Kb, Vb, rowptr, csrc, Ab, N);
  k_gemm<<<ggrid, 256, 0, stream>>>(x, Ws1, bs1, Ab, Hb, N, 1);
  // layer 2
  k_gemm<<<ggrid, 256, 0, stream>>>(Hb, Wq2, bq2, nullptr, Qb, N, 0);
  k_gemm<<<ggrid, 256, 0, stream>>>(Hb, Wk2, bk2, nullptr, Kb, N, 0);
  k_gemm<<<ggrid, 256, 0, stream>>>(Hb, Wv2, bv2, nullptr, Vb, N, 0);
  k_attn<<<(N + 3) / 4, 256, 0, stream>>>(Qb, Kb, Vb, rowptr, csrc, Ab, N);
  k_gemm<<<ggrid, 256, 0, stream>>>(Hb, Ws2, bs2, Ab, Qb, N, 1);  // layer-2 out -> Qb
  // pool + fc
  k_pool<<<256, 128, 0, stream>>>(Qb, bat, psum, pcnt, N);
  k_fc<<<G, 128, 0, stream>>>(psum, pcnt, Wfc, bfc, out);
}

// Round 2
// 580.061 us; speedup vs baseline: 1.4348x; 1.4348x over previous
//
#include <hip/hip_runtime.h>
#include <hip/hip_bf16.h>
#include <math.h>

#define HID 128

typedef __attribute__((ext_vector_type(8))) short short8;
typedef __attribute__((ext_vector_type(4))) short short4v;
typedef __attribute__((ext_vector_type(2))) short short2v;
typedef __attribute__((ext_vector_type(4))) float f32x4;
typedef __attribute__((ext_vector_type(2))) float f32x2;
typedef __attribute__((ext_vector_type(4))) unsigned short ushort4v;
typedef __attribute__((ext_vector_type(2))) unsigned short ushort2v;

static inline size_t align256(size_t x){ return (x + 255) & ~(size_t)255; }

__device__ inline float bf2f(unsigned short h) {
  union { unsigned u; float f; } uf; uf.u = ((unsigned)h) << 16; return uf.f;
}
__device__ inline unsigned short f2bf(float f) {
  union { float f; unsigned u; } uf; uf.f = f;
  unsigned r = uf.u + 0x7fff + ((uf.u >> 16) & 1);  // RNE
  return (unsigned short)(r >> 16);
}

// ---------------- weight prep: transpose + cast to bf16, concat biases ----------------
// Wcat[m][c][k] = bf16(W_m[k][c]), m in 0..7 (q1,k1,v1,s1,q2,k2,v2,s2); Bcat[m][c]
__global__ void k_wprep(const float* W0, const float* W1, const float* W2, const float* W3,
                        const float* W4, const float* W5, const float* W6, const float* W7,
                        const float* b0, const float* b1, const float* b2, const float* b3,
                        const float* b4, const float* b5, const float* b6, const float* b7,
                        unsigned short* Wcat, float* Bcat)
{
  int gid = blockIdx.x * 256 + threadIdx.x;            // 512 blocks x 256 = 131072
  const float* Ws[8] = {W0, W1, W2, W3, W4, W5, W6, W7};
  int m = gid >> 14, rem = gid & 16383, c = rem >> 7, k = rem & 127;
  Wcat[gid] = f2bf(Ws[m][k * 128 + c]);
  if (gid < 1024) {
    const float* bs[8] = {b0, b1, b2, b3, b4, b5, b6, b7};
    Bcat[gid] = bs[gid >> 7][gid & 127];
  }
}

// ---------------- CSR build ----------------
__global__ void k_hist(const int* __restrict__ dst, int* __restrict__ deg, int e) {
  for (int i = blockIdx.x * blockDim.x + threadIdx.x; i < e; i += gridDim.x * blockDim.x)
    atomicAdd(&deg[dst[i]], 1);
}

__global__ void k_scan_a(const int* __restrict__ deg, int* __restrict__ rowptr,
                         int* __restrict__ bsum, int n) {
  __shared__ int tmp[512];
  int t = threadIdx.x, i = blockIdx.x * 512 + t;
  int v = (i < n) ? deg[i] : 0;
  tmp[t] = v;
  __syncthreads();
  for (int off = 1; off < 512; off <<= 1) {
    int u = (t >= off) ? tmp[t - off] : 0;
    __syncthreads();
    tmp[t] += u;
    __syncthreads();
  }
  if (i < n) rowptr[i] = tmp[t] - v;
  if (t == 511) bsum[blockIdx.x] = tmp[t];
}

__global__ void k_scan_b(int* bsum, int nb) {
  if (threadIdx.x == 0 && blockIdx.x == 0) {
    int acc = 0;
    for (int i = 0; i < nb; ++i) { int v = bsum[i]; bsum[i] = acc; acc += v; }
  }
}

__global__ void k_scan_c(int* __restrict__ rowptr, int* __restrict__ cursor,
                         const int* __restrict__ bsum, int n, int e) {
  int i = blockIdx.x * 512 + threadIdx.x;
  if (i < n) { int v = rowptr[i] + bsum[blockIdx.x]; rowptr[i] = v; cursor[i] = v; }
  if (i == 0) rowptr[n] = e;
}

__global__ void k_scatter(const int* __restrict__ srcA, const int* __restrict__ dstA,
                          int* __restrict__ cursor, int* __restrict__ csrc, int e) {
  for (int i = blockIdx.x * blockDim.x + threadIdx.x; i < e; i += gridDim.x * blockDim.x) {
    int pos = atomicAdd(&cursor[dstA[i]], 1);
    csrc[pos] = srcA[i];
  }
}

// ---------------- fused QKVS projection GEMM (bf16 MFMA) ----------------
// grid (ceil(n/128), 4): y=0 Q(bf16), y=1 K -> KV interleave, y=2 V -> KV, y=3 S(fp32)
// A-operand = W columns (M dim), B-operand = X rows (N dim) so each lane's D frag
// is 4 consecutive cols of one row -> contiguous stores.
__global__ __launch_bounds__(256) void k_qkvs(
    const float* __restrict__ A, const unsigned short* __restrict__ Wl,
    const float* __restrict__ Bl, unsigned short* __restrict__ Qb,
    unsigned short* __restrict__ KVb, float* __restrict__ Sb, int n)
{
  __shared__ unsigned short sA[128 * 128];   // 32 KB, 16B-chunk XOR swizzled
  __shared__ unsigned short sW[128 * 128];   // 32 KB
  const int tid = threadIdx.x;
  const int rb = blockIdx.x * 128;
  const int y = blockIdx.y;

  // stage A tile: fp32 -> bf16
  #pragma unroll
  for (int it = 0; it < 16; ++it) {
    int q = tid + it * 256;
    int row = q >> 5, c4 = (q & 31) * 4;
    int gr = rb + row;
    f32x4 a = {0.f, 0.f, 0.f, 0.f};
    if (gr < n) a = *reinterpret_cast<const f32x4*>(A + (size_t)gr * HID + c4);
    short4v h;
    h.x = (short)f2bf(a.x); h.y = (short)f2bf(a.y);
    h.z = (short)f2bf(a.z); h.w = (short)f2bf(a.w);
    int eloff = row * 128 + (((c4 >> 3) ^ (row & 7)) << 3) + (c4 & 7);
    *reinterpret_cast<short4v*>(&sA[eloff]) = h;
  }
  // stage W tile (already bf16, transposed [c][k])
  const unsigned short* Wy = Wl + (size_t)y * 16384;
  #pragma unroll
  for (int it = 0; it < 8; ++it) {
    int q = tid + it * 256;
    int c = q >> 4, ch = q & 15;
    short8 w = *reinterpret_cast<const short8*>(Wy + c * 128 + ch * 8);
    int eloff = c * 128 + ((ch ^ (c & 7)) << 3);
    *reinterpret_cast<short8*>(&sW[eloff]) = w;
  }
  __syncthreads();

  const int lane = tid & 63;
  const int wv = tid >> 6;        // wave id: rows [wv*32, wv*32+32)
  f32x4 acc[8][2] = {};
  #pragma unroll
  for (int ks = 0; ks < 4; ++ks) {
    short8 af[2], wf[8];
    int ch = ks * 4 + (lane >> 4);
    #pragma unroll
    for (int nf = 0; nf < 2; ++nf) {
      int row = wv * 32 + nf * 16 + (lane & 15);
      af[nf] = *reinterpret_cast<const short8*>(&sA[row * 128 + ((ch ^ (row & 7)) << 3)]);
    }
    #pragma unroll
    for (int mf = 0; mf < 8; ++mf) {
      int wc = mf * 16 + (lane & 15);
      wf[mf] = *reinterpret_cast<const short8*>(&sW[wc * 128 + ((ch ^ (wc & 7)) << 3)]);
    }
    #pragma unroll
    for (int mf = 0; mf < 8; ++mf)
      #pragma unroll
      for (int nf = 0; nf < 2; ++nf)
        acc[mf][nf] = __builtin_amdgcn_mfma_f32_16x16x32_bf16(wf[mf], af[nf], acc[mf][nf], 0, 0, 0);
  }

  // epilogue: D lane mapping — row(N)=nf*16+(lane&15), cols(M)=mf*16+(lane>>4)*4 + r
  const float* By = Bl + y * 128;
  #pragma unroll
  for (int nf = 0; nf < 2; ++nf) {
    int gr = rb + wv * 32 + nf * 16 + (lane & 15);
    if (gr >= n) continue;
    #pragma unroll
    for (int mf = 0; mf < 8; ++mf) {
      int c0 = mf * 16 + ((lane >> 4) << 2);
      f32x4 b = *reinterpret_cast<const f32x4*>(By + c0);
      f32x4 v = acc[mf][nf];
      v.x += b.x; v.y += b.y; v.z += b.z; v.w += b.w;
      if (y == 0) {
        short4v h; h.x = (short)f2bf(v.x); h.y = (short)f2bf(v.y);
        h.z = (short)f2bf(v.z); h.w = (short)f2bf(v.w);
        *reinterpret_cast<short4v*>(Qb + (size_t)gr * HID + c0) = h;
      } else if (y == 3) {
        *reinterpret_cast<f32x4*>(Sb + (size_t)gr * HID + c0) = v;
      } else {
        // KV interleave: element i of K -> pos (i>>1)*4 + (i&1); V -> +2
        int koff = (y == 1) ? 0 : 2;
        short2v h0; h0.x = (short)f2bf(v.x); h0.y = (short)f2bf(v.y);
        short2v h1; h1.x = (short)f2bf(v.z); h1.y = (short)f2bf(v.w);
        *reinterpret_cast<short2v*>(KVb + (size_t)gr * 256 + 2 * c0 + koff) = h0;
        *reinterpret_cast<short2v*>(KVb + (size_t)gr * 256 + 2 * c0 + 4 + koff) = h1;
      }
    }
  }
}

// ---------------- fused attention + skip + relu ----------------
// one wave per node; lane l owns feature pair (2l,2l+1) of K and V (head = l>>4).
// KV row: [k0 k1 v0 v1 k2 k3 v2 v3 ...] bf16, 512B -> one 8B load/lane/edge.
__global__ __launch_bounds__(256) void k_attn2(
    const unsigned short* __restrict__ Qb, const unsigned short* __restrict__ KVb,
    const float* __restrict__ Sb, const int* __restrict__ rowptr,
    const int* __restrict__ csrc, float* __restrict__ Hout, int n)
{
  int wid = blockIdx.x * 4 + (threadIdx.x >> 6);
  if (wid >= n) return;
  int lane = threadIdx.x & 63;
  ushort2v qv = *reinterpret_cast<const ushort2v*>(Qb + (size_t)wid * HID + 2 * lane);
  float q0 = bf2f(qv.x), q1 = bf2f(qv.y);
  int e0 = rowptr[wid], e1 = rowptr[wid + 1];
  const float sc = 0.17677669529663687f;  // 1/sqrt(32)
  float m = -INFINITY, s = 0.f, a0 = 0.f, a1 = 0.f;
  ushort4v kv = {0, 0, 0, 0};
  if (e0 < e1) kv = *reinterpret_cast<const ushort4v*>(KVb + (size_t)csrc[e0] * 256 + 4 * lane);
  for (int j = e0; j < e1; ++j) {
    ushort4v kvn = kv;
    if (j + 1 < e1)  // prefetch next edge's row before the reduce chain
      kvn = *reinterpret_cast<const ushort4v*>(KVb + (size_t)csrc[j + 1] * 256 + 4 * lane);
    float k0 = bf2f(kv.x), k1 = bf2f(kv.y), v0 = bf2f(kv.z), v1 = bf2f(kv.w);
    float d = q0 * k0 + q1 * k1;
    d += __shfl_xor(d, 1); d += __shfl_xor(d, 2);
    d += __shfl_xor(d, 4); d += __shfl_xor(d, 8);   // 16-lane group = one head
    float lg = d * sc;
    float nm = fmaxf(m, lg);
    float cc = __expf(m - nm);
    float p  = __expf(lg - nm);
    s  = s * cc + p;
    a0 = a0 * cc + p * v0;
    a1 = a1 * cc + p * v1;
    m = nm;
    kv = kvn;
  }
  float inv = (s > 0.f) ? 1.f / s : 0.f;
  f32x2 sv = *reinterpret_cast<const f32x2*>(Sb + (size_t)wid * HID + 2 * lane);
  f32x2 h;
  h.x = fmaxf(a0 * inv + sv.x, 0.f);
  h.y = fmaxf(a1 * inv + sv.y, 0.f);
  *reinterpret_cast<f32x2*>(Hout + (size_t)wid * HID + 2 * lane) = h;
}

// ---------------- pooling (batch sorted) ----------------
__global__ void k_pool(const float* __restrict__ Hin, const int* __restrict__ batch,
                       float* __restrict__ psum, float* __restrict__ pcnt, int n) {
  int t = threadIdx.x;  // 128 threads, one per column
  int chunk = (n + gridDim.x - 1) / gridDim.x;
  int n0 = blockIdx.x * chunk, n1 = min(n, n0 + chunk);
  if (n0 >= n1) return;
  int curg = batch[n0];
  float acc = 0.f; int c = 0;
  for (int i = n0; i < n1; ++i) {
    int g = batch[i];
    if (g != curg) {
      atomicAdd(&psum[curg * HID + t], acc);
      if (t == 0) atomicAdd(&pcnt[curg], (float)c);
      acc = 0.f; c = 0; curg = g;
    }
    acc += Hin[(size_t)i * HID + t]; ++c;
  }
  atomicAdd(&psum[curg * HID + t], acc);
  if (t == 0) atomicAdd(&pcnt[curg], (float)c);
}

__global__ void k_fc(const float* __restrict__ psum, const float* __restrict__ pcnt,
                     const float* __restrict__ Wfc, const float* __restrict__ bfc,
                     float* __restrict__ out) {
  __shared__ float red[2];
  int g = blockIdx.x, t = threadIdx.x;  // 128 threads
  float v = psum[g * HID + t] * Wfc[t];
  #pragma unroll
  for (int off = 32; off >= 1; off >>= 1) v += __shfl_xor(v, off);
  if ((t & 63) == 0) red[t >> 6] = v;
  __syncthreads();
  if (t == 0) out[g] = (red[0] + red[1]) / fmaxf(pcnt[g], 1.f) + bfc[0];
}

extern "C" void kernel_launch(void* const* d_in, const int* in_sizes, int n_in,
                              void* d_out, int out_size, void* d_ws, size_t ws_size,
                              hipStream_t stream)
{
  const float* x   = (const float*)d_in[0];
  const int*   ei  = (const int*)d_in[1];
  const int*   bat = (const int*)d_in[2];
  const float *Wq1 = (const float*)d_in[3],  *bq1 = (const float*)d_in[4];
  const float *Wk1 = (const float*)d_in[5],  *bk1 = (const float*)d_in[6];
  const float *Wv1 = (const float*)d_in[7],  *bv1 = (const float*)d_in[8];
  const float *Ws1 = (const float*)d_in[9],  *bs1 = (const float*)d_in[10];
  const float *Wq2 = (const float*)d_in[11], *bq2 = (const float*)d_in[12];
  const float *Wk2 = (const float*)d_in[13], *bk2 = (const float*)d_in[14];
  const float *Wv2 = (const float*)d_in[15], *bv2 = (const float*)d_in[16];
  const float *Ws2 = (const float*)d_in[17], *bs2 = (const float*)d_in[18];
  const float *Wfc = (const float*)d_in[19], *bfc = (const float*)d_in[20];
  float* out = (float*)d_out;

  const int N = in_sizes[0] / HID;
  const int E = in_sizes[1] / 2;
  const int G = 64;

  char* p = (char*)d_ws;
  auto alloc = [&](size_t bytes) -> char* { char* r = p; p += align256(bytes); return r; };
  unsigned short* Qb  = (unsigned short*)alloc((size_t)N * HID * 2);
  unsigned short* KVb = (unsigned short*)alloc((size_t)N * 256 * 2);
  float* Sb   = (float*)alloc((size_t)N * HID * 4);
  float* Hb   = (float*)alloc((size_t)N * HID * 4);   // layer-1 output
  float* H2b  = (float*)alloc((size_t)N * HID * 4);   // layer-2 output
  unsigned short* Wcat = (unsigned short*)alloc((size_t)8 * 128 * 128 * 2);
  float* Bcat = (float*)alloc((size_t)8 * 128 * 4);
  int* rowptr = (int*)alloc((size_t)(N + 1) * sizeof(int));
  int* cursor = (int*)alloc((size_t)N * sizeof(int));
  int* deg    = (int*)alloc((size_t)N * sizeof(int));
  int* bsum   = (int*)alloc(4096);
  int* csrc   = (int*)alloc((size_t)E * sizeof(int));
  float* psum = (float*)alloc((size_t)G * HID * sizeof(float));
  float* pcnt = (float*)alloc((size_t)G * sizeof(float));

  const int* esrc = ei;
  const int* edst = ei + E;

  hipMemsetAsync(deg, 0, (size_t)N * sizeof(int), stream);
  hipMemsetAsync(psum, 0, (size_t)G * HID * sizeof(float), stream);
  hipMemsetAsync(pcnt, 0, (size_t)G * sizeof(float), stream);

  k_wprep<<<512, 256, 0, stream>>>(Wq1, Wk1, Wv1, Ws1, Wq2, Wk2, Wv2, Ws2,
                                   bq1, bk1, bv1, bs1, bq2, bk2, bv2, bs2, Wcat, Bcat);

  k_hist<<<512, 256, 0, stream>>>(edst, deg, E);
  int SB = (N + 511) / 512;
  k_scan_a<<<SB, 512, 0, stream>>>(deg, rowptr, bsum, N);
  k_scan_b<<<1, 1, 0, stream>>>(bsum, SB);
  k_scan_c<<<SB, 512, 0, stream>>>(rowptr, cursor, bsum, N, E);
  k_scatter<<<512, 256, 0, stream>>>(esrc, edst, cursor, csrc, E);

  dim3 ggrid((N + 127) / 128, 4);
  // layer 1
  k_qkvs<<<ggrid, 256, 0, stream>>>(x, Wcat, Bcat, Qb, KVb, Sb, N);
  k_attn2<<<(N + 3) / 4, 256, 0, stream>>>(Qb, KVb, Sb, rowptr, csrc, Hb, N);
  // layer 2
  k_qkvs<<<ggrid, 256, 0, stream>>>(Hb, Wcat + 4 * 16384, Bcat + 512, Qb, KVb, Sb, N);
  k_attn2<<<(N + 3) / 4, 256, 0, stream>>>(Qb, KVb, Sb, rowptr, csrc, H2b, N);
  // pool + fc
  k_pool<<<256, 128, 0, stream>>>(H2b, bat, psum, pcnt, N);
  k_fc<<<G, 128, 0, stream>>>(psum, pcnt, Wfc, bfc, out);
}

// Round 3
// 453.947 us; speedup vs baseline: 1.8334x; 1.2778x over previous
//
#include <hip/hip_runtime.h>
#include <hip/hip_bf16.h>
#include <math.h>

#define HID 128

typedef __attribute__((ext_vector_type(8))) short short8;
typedef __attribute__((ext_vector_type(4))) short short4v;
typedef __attribute__((ext_vector_type(4))) float f32x4;
typedef __attribute__((ext_vector_type(2))) float f32x2;
typedef __attribute__((ext_vector_type(4))) unsigned short ushort4v;
typedef __attribute__((ext_vector_type(2))) unsigned short ushort2v;

static inline size_t align256(size_t x){ return (x + 255) & ~(size_t)255; }

__device__ inline float bf2f(unsigned short h) {
  union { unsigned u; float f; } uf; uf.u = ((unsigned)h) << 16; return uf.f;
}
__device__ inline unsigned short f2bf(float f) {
  union { float f; unsigned u; } uf; uf.f = f;
  unsigned r = uf.u + 0x7fff + ((uf.u >> 16) & 1);  // RNE
  return (unsigned short)(r >> 16);
}

// sum across each 16-lane group (DPP row) — pure VALU, no LDS pipe
__device__ inline float dpp_rsum16(float x) {
  int v;
  v = __builtin_amdgcn_update_dpp(0, __float_as_int(x), 0xB1, 0xF, 0xF, true);  // quad_perm [1,0,3,2]
  x += __int_as_float(v);
  v = __builtin_amdgcn_update_dpp(0, __float_as_int(x), 0x4E, 0xF, 0xF, true);  // quad_perm [2,3,0,1]
  x += __int_as_float(v);
  v = __builtin_amdgcn_update_dpp(0, __float_as_int(x), 0x124, 0xF, 0xF, true); // row_ror:4
  x += __int_as_float(v);
  v = __builtin_amdgcn_update_dpp(0, __float_as_int(x), 0x128, 0xF, 0xF, true); // row_ror:8
  x += __int_as_float(v);
  return x;
}

// ---------------- weight prep: coalesced LDS transpose, fp32 -> bf16 ----------------
// Wcat[m][c][k] = bf16(W_m[k][c]); grid = 8 matrices x 16 (4x4) 32x32 tiles
__global__ __launch_bounds__(256) void k_wprep(
    const float* W0, const float* W1, const float* W2, const float* W3,
    const float* W4, const float* W5, const float* W6, const float* W7,
    const float* b0, const float* b1, const float* b2, const float* b3,
    const float* b4, const float* b5, const float* b6, const float* b7,
    unsigned short* Wcat, float* Bcat)
{
  __shared__ float tl[32][33];
  const float* Ws[8] = {W0, W1, W2, W3, W4, W5, W6, W7};
  const float* bs[8] = {b0, b1, b2, b3, b4, b5, b6, b7};
  int m = blockIdx.x >> 4, tile = blockIdx.x & 15;
  int tr = (tile >> 2) * 32, tc = (tile & 3) * 32;   // tile origin: row (k), col (c)
  int tx = threadIdx.x & 31, ty = threadIdx.x >> 5;  // 32 x 8
  const float* Wm = Ws[m];
  #pragma unroll
  for (int r = 0; r < 32; r += 8) tl[ty + r][tx] = Wm[(tr + ty + r) * 128 + tc + tx];
  __syncthreads();
  #pragma unroll
  for (int r = 0; r < 32; r += 8)
    Wcat[m * 16384 + (tc + ty + r) * 128 + tr + tx] = f2bf(tl[tx][ty + r]);
  if (tile == 0 && threadIdx.x < 128) Bcat[m * 128 + threadIdx.x] = bs[m][threadIdx.x];
}

// ---------------- CSR build ----------------
__global__ void k_hist(const int* __restrict__ dst, int* __restrict__ deg, int e) {
  for (int i = blockIdx.x * blockDim.x + threadIdx.x; i < e; i += gridDim.x * blockDim.x)
    atomicAdd(&deg[dst[i]], 1);
}

__global__ void k_scan_a(const int* __restrict__ deg, int* __restrict__ rowptr,
                         int* __restrict__ bsum, int n) {
  __shared__ int tmp[512];
  int t = threadIdx.x, i = blockIdx.x * 512 + t;
  int v = (i < n) ? deg[i] : 0;
  tmp[t] = v;
  __syncthreads();
  for (int off = 1; off < 512; off <<= 1) {
    int u = (t >= off) ? tmp[t - off] : 0;
    __syncthreads();
    tmp[t] += u;
    __syncthreads();
  }
  if (i < n) rowptr[i] = tmp[t] - v;
  if (t == 511) bsum[blockIdx.x] = tmp[t];
}

// parallel exclusive scan of <=512 block sums (was single-threaded)
__global__ void k_scan_b(int* bsum, int nb) {
  __shared__ int tmp[512];
  int t = threadIdx.x;
  int v = (t < nb) ? bsum[t] : 0;
  tmp[t] = v;
  __syncthreads();
  for (int off = 1; off < 512; off <<= 1) {
    int u = (t >= off) ? tmp[t - off] : 0;
    __syncthreads();
    tmp[t] += u;
    __syncthreads();
  }
  if (t < nb) bsum[t] = tmp[t] - v;
}

__global__ void k_scan_c(int* __restrict__ rowptr, int* __restrict__ cursor,
                         const int* __restrict__ bsum, int n, int e) {
  int i = blockIdx.x * 512 + threadIdx.x;
  if (i < n) { int v = rowptr[i] + bsum[blockIdx.x]; rowptr[i] = v; cursor[i] = v; }
  if (i == 0) rowptr[n] = e;
}

__global__ void k_scatter(const int* __restrict__ srcA, const int* __restrict__ dstA,
                          int* __restrict__ cursor, int* __restrict__ csrc, int e) {
  for (int i = blockIdx.x * blockDim.x + threadIdx.x; i < e; i += gridDim.x * blockDim.x) {
    int pos = atomicAdd(&cursor[dstA[i]], 1);
    csrc[pos] = srcA[i];
  }
}

// ---------------- fused QKVS projection GEMM (bf16 MFMA, 4 phases / block) ----------------
// One block owns a 128-row tile; A staged once (fragments kept in registers),
// W for Q,S,K,V cycled through one LDS buffer. K acc held live so V phase
// emits interleaved KV rows as single 16B stores.
template<int ABF16>
__global__ __launch_bounds__(256, 2) void k_qkvs(
    const void* __restrict__ Ain, const unsigned short* __restrict__ Wl,
    const float* __restrict__ Bl, unsigned short* __restrict__ Qb,
    unsigned short* __restrict__ KVb, float* __restrict__ Sb, int n)
{
  __shared__ unsigned short sA[128 * 128];
  __shared__ unsigned short sW[128 * 128];
  const int tid = threadIdx.x;
  const int rb = blockIdx.x * 128;

  // stage A tile (16B-chunk XOR swizzle)
  if (ABF16) {
    const unsigned short* A = (const unsigned short*)Ain;
    #pragma unroll
    for (int it = 0; it < 8; ++it) {
      int q = tid + it * 256;
      int row = q >> 4, ch = q & 15;
      int gr = rb + row;
      short8 h = {0,0,0,0,0,0,0,0};
      if (gr < n) h = *reinterpret_cast<const short8*>(A + (size_t)gr * HID + ch * 8);
      *reinterpret_cast<short8*>(&sA[row * 128 + ((ch ^ (row & 7)) << 3)]) = h;
    }
  } else {
    const float* A = (const float*)Ain;
    #pragma unroll
    for (int it = 0; it < 16; ++it) {
      int q = tid + it * 256;
      int row = q >> 5, c4 = (q & 31) * 4;
      int gr = rb + row;
      f32x4 a = {0.f, 0.f, 0.f, 0.f};
      if (gr < n) a = *reinterpret_cast<const f32x4*>(A + (size_t)gr * HID + c4);
      short4v h;
      h.x = (short)f2bf(a.x); h.y = (short)f2bf(a.y);
      h.z = (short)f2bf(a.z); h.w = (short)f2bf(a.w);
      int eloff = row * 128 + (((c4 >> 3) ^ (row & 7)) << 3) + (c4 & 7);
      *reinterpret_cast<short4v*>(&sA[eloff]) = h;
    }
  }

  const int lane = tid & 63;
  const int wv = tid >> 6;

  auto stageW = [&](int y) {
    const unsigned short* Wy = Wl + (size_t)y * 16384;
    #pragma unroll
    for (int it = 0; it < 8; ++it) {
      int q = tid + it * 256;
      int c = q >> 4, ch = q & 15;
      short8 w = *reinterpret_cast<const short8*>(Wy + c * 128 + ch * 8);
      *reinterpret_cast<short8*>(&sW[c * 128 + ((ch ^ (c & 7)) << 3)]) = w;
    }
  };

  stageW(0);           // Wq staged alongside A
  __syncthreads();

  // A fragments -> registers once, reused across all 4 phases
  short8 af[4][2];
  #pragma unroll
  for (int ks = 0; ks < 4; ++ks) {
    int ch = ks * 4 + (lane >> 4);
    #pragma unroll
    for (int nf = 0; nf < 2; ++nf) {
      int row = wv * 32 + nf * 16 + (lane & 15);
      af[ks][nf] = *reinterpret_cast<const short8*>(&sA[row * 128 + ((ch ^ (row & 7)) << 3)]);
    }
  }

  f32x4 acc[8][2];
  auto compute = [&]() {
    #pragma unroll
    for (int mf = 0; mf < 8; ++mf)
      #pragma unroll
      for (int nf = 0; nf < 2; ++nf)
        acc[mf][nf] = (f32x4){0.f, 0.f, 0.f, 0.f};
    #pragma unroll
    for (int ks = 0; ks < 4; ++ks) {
      int ch = ks * 4 + (lane >> 4);
      short8 wf[8];
      #pragma unroll
      for (int mf = 0; mf < 8; ++mf) {
        int wc = mf * 16 + (lane & 15);
        wf[mf] = *reinterpret_cast<const short8*>(&sW[wc * 128 + ((ch ^ (wc & 7)) << 3)]);
      }
      #pragma unroll
      for (int mf = 0; mf < 8; ++mf)
        #pragma unroll
        for (int nf = 0; nf < 2; ++nf)
          acc[mf][nf] = __builtin_amdgcn_mfma_f32_16x16x32_bf16(wf[mf], af[ks][nf], acc[mf][nf], 0, 0, 0);
    }
  };

  // ---- phase 0: Q ----
  compute();
  #pragma unroll
  for (int nf = 0; nf < 2; ++nf) {
    int gr = rb + wv * 32 + nf * 16 + (lane & 15);
    if (gr >= n) continue;
    #pragma unroll
    for (int mf = 0; mf < 8; ++mf) {
      int c0 = mf * 16 + ((lane >> 4) << 2);
      f32x4 b = *reinterpret_cast<const f32x4*>(Bl + 0 * 128 + c0);
      f32x4 v = acc[mf][nf];
      short4v h;
      h.x = (short)f2bf(v.x + b.x); h.y = (short)f2bf(v.y + b.y);
      h.z = (short)f2bf(v.z + b.z); h.w = (short)f2bf(v.w + b.w);
      *reinterpret_cast<short4v*>(Qb + (size_t)gr * HID + c0) = h;
    }
  }

  // ---- phase 1: S (fp32) ----
  __syncthreads();
  stageW(3);
  __syncthreads();
  compute();
  #pragma unroll
  for (int nf = 0; nf < 2; ++nf) {
    int gr = rb + wv * 32 + nf * 16 + (lane & 15);
    if (gr >= n) continue;
    #pragma unroll
    for (int mf = 0; mf < 8; ++mf) {
      int c0 = mf * 16 + ((lane >> 4) << 2);
      f32x4 b = *reinterpret_cast<const f32x4*>(Bl + 3 * 128 + c0);
      f32x4 v = acc[mf][nf];
      v.x += b.x; v.y += b.y; v.z += b.z; v.w += b.w;
      *reinterpret_cast<f32x4*>(Sb + (size_t)gr * HID + c0) = v;
    }
  }

  // ---- phase 2: K (held in registers) ----
  __syncthreads();
  stageW(1);
  __syncthreads();
  compute();
  f32x4 kacc[8][2];
  #pragma unroll
  for (int mf = 0; mf < 8; ++mf)
    #pragma unroll
    for (int nf = 0; nf < 2; ++nf) kacc[mf][nf] = acc[mf][nf];

  // ---- phase 3: V, store interleaved KV ----
  __syncthreads();
  stageW(2);
  __syncthreads();
  compute();
  #pragma unroll
  for (int nf = 0; nf < 2; ++nf) {
    int gr = rb + wv * 32 + nf * 16 + (lane & 15);
    if (gr >= n) continue;
    #pragma unroll
    for (int mf = 0; mf < 8; ++mf) {
      int c0 = mf * 16 + ((lane >> 4) << 2);
      f32x4 bk = *reinterpret_cast<const f32x4*>(Bl + 1 * 128 + c0);
      f32x4 bv = *reinterpret_cast<const f32x4*>(Bl + 2 * 128 + c0);
      f32x4 kv = kacc[mf][nf], vv = acc[mf][nf];
      // pairs p: [k(2p) k(2p+1) v(2p) v(2p+1)]
      short8 h;
      h[0] = (short)f2bf(kv.x + bk.x); h[1] = (short)f2bf(kv.y + bk.y);
      h[2] = (short)f2bf(vv.x + bv.x); h[3] = (short)f2bf(vv.y + bv.y);
      h[4] = (short)f2bf(kv.z + bk.z); h[5] = (short)f2bf(kv.w + bk.w);
      h[6] = (short)f2bf(vv.z + bv.z); h[7] = (short)f2bf(vv.w + bv.w);
      *reinterpret_cast<short8*>(KVb + (size_t)gr * 256 + 2 * c0) = h;
    }
  }
}

// ---------------- fused attention + skip + relu (DPP reduce, 4-deep pipeline) ----------------
__global__ __launch_bounds__(256) void k_attn2(
    const unsigned short* __restrict__ Qb, const unsigned short* __restrict__ KVb,
    const float* __restrict__ Sb, const int* __restrict__ rowptr,
    const int* __restrict__ csrc, unsigned short* __restrict__ Hout, int n)
{
  int wid = blockIdx.x * 4 + (threadIdx.x >> 6);
  if (wid >= n) return;
  int lane = threadIdx.x & 63;
  ushort2v qv = *reinterpret_cast<const ushort2v*>(Qb + (size_t)wid * HID + 2 * lane);
  const float sc = 0.17677669529663687f;  // 1/sqrt(32), folded into q
  float q0 = bf2f(qv.x) * sc, q1 = bf2f(qv.y) * sc;
  int e0 = rowptr[wid], deg = rowptr[wid + 1] - e0;
  const int* cp = csrc + e0;
  float m = -INFINITY, s = 0.f, a0 = 0.f, a1 = 0.f;

  auto LD = [&](int i) -> ushort4v {
    return *reinterpret_cast<const ushort4v*>(KVb + (size_t)cp[i] * 256 + 4 * lane);
  };
  auto proc = [&](ushort4v kv) {
    float d = q0 * bf2f(kv.x) + q1 * bf2f(kv.y);
    float lg = dpp_rsum16(d);
    float nm = fmaxf(m, lg);
    float cc = __expf(m - nm);
    float p  = __expf(lg - nm);
    s  = s * cc + p;
    a0 = a0 * cc + p * bf2f(kv.z);
    a1 = a1 * cc + p * bf2f(kv.w);
    m = nm;
  };

  ushort4v z = {0, 0, 0, 0};
  ushort4v b0 = z, b1 = z, b2 = z, b3 = z;
  if (deg > 0) b0 = LD(0);
  if (deg > 1) b1 = LD(1);
  if (deg > 2) b2 = LD(2);
  if (deg > 3) b3 = LD(3);
  for (int j = 0; j < deg; j += 4) {
    ushort4v n0 = z, n1 = z, n2 = z, n3 = z;
    if (j + 4 < deg) n0 = LD(j + 4);
    if (j + 5 < deg) n1 = LD(j + 5);
    if (j + 6 < deg) n2 = LD(j + 6);
    if (j + 7 < deg) n3 = LD(j + 7);
    proc(b0);
    if (j + 1 < deg) proc(b1);
    if (j + 2 < deg) proc(b2);
    if (j + 3 < deg) proc(b3);
    b0 = n0; b1 = n1; b2 = n2; b3 = n3;
  }
  float inv = (s > 0.f) ? 1.f / s : 0.f;
  f32x2 sv = *reinterpret_cast<const f32x2*>(Sb + (size_t)wid * HID + 2 * lane);
  ushort2v h;
  h.x = f2bf(fmaxf(a0 * inv + sv.x, 0.f));
  h.y = f2bf(fmaxf(a1 * inv + sv.y, 0.f));
  *reinterpret_cast<ushort2v*>(Hout + (size_t)wid * HID + 2 * lane) = h;
}

// ---------------- pooling (batch sorted, bf16 input) ----------------
__global__ void k_pool(const unsigned short* __restrict__ Hin, const int* __restrict__ batch,
                       float* __restrict__ psum, float* __restrict__ pcnt, int n) {
  int t = threadIdx.x;  // 128 threads, one per column
  int chunk = (n + gridDim.x - 1) / gridDim.x;
  int n0 = blockIdx.x * chunk, n1 = min(n, n0 + chunk);
  if (n0 >= n1) return;
  int curg = batch[n0];
  float acc = 0.f; int c = 0;
  for (int i = n0; i < n1; ++i) {
    int g = batch[i];
    if (g != curg) {
      atomicAdd(&psum[curg * HID + t], acc);
      if (t == 0) atomicAdd(&pcnt[curg], (float)c);
      acc = 0.f; c = 0; curg = g;
    }
    acc += bf2f(Hin[(size_t)i * HID + t]); ++c;
  }
  atomicAdd(&psum[curg * HID + t], acc);
  if (t == 0) atomicAdd(&pcnt[curg], (float)c);
}

__global__ void k_fc(const float* __restrict__ psum, const float* __restrict__ pcnt,
                     const float* __restrict__ Wfc, const float* __restrict__ bfc,
                     float* __restrict__ out) {
  __shared__ float red[2];
  int g = blockIdx.x, t = threadIdx.x;  // 128 threads
  float v = psum[g * HID + t] * Wfc[t];
  #pragma unroll
  for (int off = 32; off >= 1; off >>= 1) v += __shfl_xor(v, off);
  if ((t & 63) == 0) red[t >> 6] = v;
  __syncthreads();
  if (t == 0) out[g] = (red[0] + red[1]) / fmaxf(pcnt[g], 1.f) + bfc[0];
}

extern "C" void kernel_launch(void* const* d_in, const int* in_sizes, int n_in,
                              void* d_out, int out_size, void* d_ws, size_t ws_size,
                              hipStream_t stream)
{
  const float* x   = (const float*)d_in[0];
  const int*   ei  = (const int*)d_in[1];
  const int*   bat = (const int*)d_in[2];
  const float *Wq1 = (const float*)d_in[3],  *bq1 = (const float*)d_in[4];
  const float *Wk1 = (const float*)d_in[5],  *bk1 = (const float*)d_in[6];
  const float *Wv1 = (const float*)d_in[7],  *bv1 = (const float*)d_in[8];
  const float *Ws1 = (const float*)d_in[9],  *bs1 = (const float*)d_in[10];
  const float *Wq2 = (const float*)d_in[11], *bq2 = (const float*)d_in[12];
  const float *Wk2 = (const float*)d_in[13], *bk2 = (const float*)d_in[14];
  const float *Wv2 = (const float*)d_in[15], *bv2 = (const float*)d_in[16];
  const float *Ws2 = (const float*)d_in[17], *bs2 = (const float*)d_in[18];
  const float *Wfc = (const float*)d_in[19], *bfc = (const float*)d_in[20];
  float* out = (float*)d_out;

  const int N = in_sizes[0] / HID;
  const int E = in_sizes[1] / 2;
  const int G = 64;

  char* p = (char*)d_ws;
  auto alloc = [&](size_t bytes) -> char* { char* r = p; p += align256(bytes); return r; };
  unsigned short* Qb  = (unsigned short*)alloc((size_t)N * HID * 2);
  unsigned short* KVb = (unsigned short*)alloc((size_t)N * 256 * 2);
  float* Sb   = (float*)alloc((size_t)N * HID * 4);
  unsigned short* Hb  = (unsigned short*)alloc((size_t)N * HID * 2);  // layer-1 out (bf16)
  unsigned short* H2b = (unsigned short*)alloc((size_t)N * HID * 2);  // layer-2 out (bf16)
  unsigned short* Wcat = (unsigned short*)alloc((size_t)8 * 128 * 128 * 2);
  float* Bcat = (float*)alloc((size_t)8 * 128 * 4);
  int* rowptr = (int*)alloc((size_t)(N + 1) * sizeof(int));
  int* cursor = (int*)alloc((size_t)N * sizeof(int));
  int* deg    = (int*)alloc((size_t)N * sizeof(int));
  int* bsum   = (int*)alloc(4096);
  int* csrc   = (int*)alloc((size_t)E * sizeof(int));
  float* psum = (float*)alloc((size_t)G * HID * sizeof(float));
  float* pcnt = (float*)alloc((size_t)G * sizeof(float));

  const int* esrc = ei;
  const int* edst = ei + E;

  hipMemsetAsync(deg, 0, (size_t)N * sizeof(int), stream);
  hipMemsetAsync(psum, 0, (size_t)G * HID * sizeof(float), stream);
  hipMemsetAsync(pcnt, 0, (size_t)G * sizeof(float), stream);

  k_wprep<<<128, 256, 0, stream>>>(Wq1, Wk1, Wv1, Ws1, Wq2, Wk2, Wv2, Ws2,
                                   bq1, bk1, bv1, bs1, bq2, bk2, bv2, bs2, Wcat, Bcat);

  k_hist<<<512, 256, 0, stream>>>(edst, deg, E);
  int SB = (N + 511) / 512;
  k_scan_a<<<SB, 512, 0, stream>>>(deg, rowptr, bsum, N);
  k_scan_b<<<1, 512, 0, stream>>>(bsum, SB);
  k_scan_c<<<SB, 512, 0, stream>>>(rowptr, cursor, bsum, N, E);
  k_scatter<<<512, 256, 0, stream>>>(esrc, edst, cursor, csrc, E);

  int QB = (N + 127) / 128;
  // layer 1 (fp32 input)
  k_qkvs<0><<<QB, 256, 0, stream>>>(x, Wcat, Bcat, Qb, KVb, Sb, N);
  k_attn2<<<(N + 3) / 4, 256, 0, stream>>>(Qb, KVb, Sb, rowptr, csrc, Hb, N);
  // layer 2 (bf16 input)
  k_qkvs<1><<<QB, 256, 0, stream>>>(Hb, Wcat + 4 * 16384, Bcat + 512, Qb, KVb, Sb, N);
  k_attn2<<<(N + 3) / 4, 256, 0, stream>>>(Qb, KVb, Sb, rowptr, csrc, H2b, N);
  // pool + fc
  k_pool<<<1024, 128, 0, stream>>>(H2b, bat, psum, pcnt, N);
  k_fc<<<G, 128, 0, stream>>>(psum, pcnt, Wfc, bfc, out);
}

// Round 4
// 410.564 us; speedup vs baseline: 2.0271x; 1.1057x over previous
//
#include <hip/hip_runtime.h>
#include <hip/hip_bf16.h>
#include <math.h>

#define HID 128

typedef __attribute__((ext_vector_type(8))) short short8;
typedef __attribute__((ext_vector_type(4))) short short4v;
typedef __attribute__((ext_vector_type(4))) float f32x4;
typedef __attribute__((ext_vector_type(2))) float f32x2;
typedef __attribute__((ext_vector_type(4))) unsigned short ushort4v;
typedef __attribute__((ext_vector_type(2))) unsigned short ushort2v;

static inline size_t align256(size_t x){ return (x + 255) & ~(size_t)255; }

__device__ inline float bf2f(unsigned short h) {
  union { unsigned u; float f; } uf; uf.u = ((unsigned)h) << 16; return uf.f;
}
__device__ inline unsigned short f2bf(float f) {
  union { float f; unsigned u; } uf; uf.f = f;
  unsigned r = uf.u + 0x7fff + ((uf.u >> 16) & 1);  // RNE
  return (unsigned short)(r >> 16);
}

// sum across each 16-lane group (DPP row) — pure VALU, no LDS pipe
__device__ inline float dpp_rsum16(float x) {
  int v;
  v = __builtin_amdgcn_update_dpp(0, __float_as_int(x), 0xB1, 0xF, 0xF, true);  // quad_perm [1,0,3,2]
  x += __int_as_float(v);
  v = __builtin_amdgcn_update_dpp(0, __float_as_int(x), 0x4E, 0xF, 0xF, true);  // quad_perm [2,3,0,1]
  x += __int_as_float(v);
  v = __builtin_amdgcn_update_dpp(0, __float_as_int(x), 0x124, 0xF, 0xF, true); // row_ror:4
  x += __int_as_float(v);
  v = __builtin_amdgcn_update_dpp(0, __float_as_int(x), 0x128, 0xF, 0xF, true); // row_ror:8
  x += __int_as_float(v);
  return x;
}

// ---------------- weight prep: coalesced LDS transpose, fp32 -> bf16 ----------------
__global__ __launch_bounds__(256) void k_wprep(
    const float* W0, const float* W1, const float* W2, const float* W3,
    const float* W4, const float* W5, const float* W6, const float* W7,
    const float* b0, const float* b1, const float* b2, const float* b3,
    const float* b4, const float* b5, const float* b6, const float* b7,
    unsigned short* Wcat, float* Bcat)
{
  __shared__ float tl[32][33];
  const float* Ws[8] = {W0, W1, W2, W3, W4, W5, W6, W7};
  const float* bs[8] = {b0, b1, b2, b3, b4, b5, b6, b7};
  int m = blockIdx.x >> 4, tile = blockIdx.x & 15;
  int tr = (tile >> 2) * 32, tc = (tile & 3) * 32;
  int tx = threadIdx.x & 31, ty = threadIdx.x >> 5;
  const float* Wm = Ws[m];
  #pragma unroll
  for (int r = 0; r < 32; r += 8) tl[ty + r][tx] = Wm[(tr + ty + r) * 128 + tc + tx];
  __syncthreads();
  #pragma unroll
  for (int r = 0; r < 32; r += 8)
    Wcat[m * 16384 + (tc + ty + r) * 128 + tr + tx] = f2bf(tl[tx][ty + r]);
  if (tile == 0 && threadIdx.x < 128) Bcat[m * 128 + threadIdx.x] = bs[m][threadIdx.x];
}

// ---------------- CSR build ----------------
__global__ void k_hist(const int* __restrict__ dst, int* __restrict__ deg, int e) {
  for (int i = blockIdx.x * blockDim.x + threadIdx.x; i < e; i += gridDim.x * blockDim.x)
    atomicAdd(&deg[dst[i]], 1);
}

__global__ void k_scan_a(const int* __restrict__ deg, int* __restrict__ rowptr,
                         int* __restrict__ bsum, int n) {
  __shared__ int tmp[512];
  int t = threadIdx.x, i = blockIdx.x * 512 + t;
  int v = (i < n) ? deg[i] : 0;
  tmp[t] = v;
  __syncthreads();
  for (int off = 1; off < 512; off <<= 1) {
    int u = (t >= off) ? tmp[t - off] : 0;
    __syncthreads();
    tmp[t] += u;
    __syncthreads();
  }
  if (i < n) rowptr[i] = tmp[t] - v;
  if (t == 511) bsum[blockIdx.x] = tmp[t];
}

__global__ void k_scan_b(int* bsum, int nb) {
  __shared__ int tmp[512];
  int t = threadIdx.x;
  int v = (t < nb) ? bsum[t] : 0;
  tmp[t] = v;
  __syncthreads();
  for (int off = 1; off < 512; off <<= 1) {
    int u = (t >= off) ? tmp[t - off] : 0;
    __syncthreads();
    tmp[t] += u;
    __syncthreads();
  }
  if (t < nb) bsum[t] = tmp[t] - v;
}

__global__ void k_scan_c(int* __restrict__ rowptr, int* __restrict__ cursor,
                         const int* __restrict__ bsum, int n, int e) {
  int i = blockIdx.x * 512 + threadIdx.x;
  if (i < n) { int v = rowptr[i] + bsum[blockIdx.x]; rowptr[i] = v; cursor[i] = v; }
  if (i == 0) rowptr[n] = e;
}

// csrc holds BYTE offsets into KVb (src * 512) — kills per-edge 64-bit mul in attn
__global__ void k_scatter(const int* __restrict__ srcA, const int* __restrict__ dstA,
                          int* __restrict__ cursor, int* __restrict__ csrc, int e) {
  for (int i = blockIdx.x * blockDim.x + threadIdx.x; i < e; i += gridDim.x * blockDim.x) {
    int pos = atomicAdd(&cursor[dstA[i]], 1);
    csrc[pos] = srcA[i] << 9;
  }
}

// ---------------- fused QKVS projection GEMM (bf16 MFMA, 64-row tiles, 4 phases) ----------------
template<int ABF16>
__global__ __launch_bounds__(256, 2) void k_qkvs(
    const void* __restrict__ Ain, const unsigned short* __restrict__ Wl,
    const float* __restrict__ Bl, unsigned short* __restrict__ Qb,
    unsigned short* __restrict__ KVb, float* __restrict__ Sb, int n)
{
  __shared__ unsigned short sA[64 * 128];    // 16 KB
  __shared__ unsigned short sW[128 * 128];   // 32 KB
  const int tid = threadIdx.x;
  const int rb = blockIdx.x * 64;

  if (ABF16) {
    const unsigned short* A = (const unsigned short*)Ain;
    #pragma unroll
    for (int it = 0; it < 4; ++it) {
      int q = tid + it * 256;
      int row = q >> 4, ch = q & 15;
      int gr = rb + row;
      short8 h = {0,0,0,0,0,0,0,0};
      if (gr < n) h = *reinterpret_cast<const short8*>(A + (size_t)gr * HID + ch * 8);
      *reinterpret_cast<short8*>(&sA[row * 128 + ((ch ^ (row & 7)) << 3)]) = h;
    }
  } else {
    const float* A = (const float*)Ain;
    #pragma unroll
    for (int it = 0; it < 8; ++it) {
      int q = tid + it * 256;
      int row = q >> 5, c4 = (q & 31) * 4;
      int gr = rb + row;
      f32x4 a = {0.f, 0.f, 0.f, 0.f};
      if (gr < n) a = *reinterpret_cast<const f32x4*>(A + (size_t)gr * HID + c4);
      short4v h;
      h.x = (short)f2bf(a.x); h.y = (short)f2bf(a.y);
      h.z = (short)f2bf(a.z); h.w = (short)f2bf(a.w);
      int eloff = row * 128 + (((c4 >> 3) ^ (row & 7)) << 3) + (c4 & 7);
      *reinterpret_cast<short4v*>(&sA[eloff]) = h;
    }
  }

  const int lane = tid & 63;
  const int wv = tid >> 6;

  auto stageW = [&](int y) {
    const unsigned short* Wy = Wl + (size_t)y * 16384;
    #pragma unroll
    for (int it = 0; it < 8; ++it) {
      int q = tid + it * 256;
      int c = q >> 4, ch = q & 15;
      short8 w = *reinterpret_cast<const short8*>(Wy + c * 128 + ch * 8);
      *reinterpret_cast<short8*>(&sW[c * 128 + ((ch ^ (c & 7)) << 3)]) = w;
    }
  };

  stageW(0);
  __syncthreads();

  // A fragments -> registers once, reused across all 4 phases
  short8 af[4];
  #pragma unroll
  for (int ks = 0; ks < 4; ++ks) {
    int ch = ks * 4 + (lane >> 4);
    int row = wv * 16 + (lane & 15);
    af[ks] = *reinterpret_cast<const short8*>(&sA[row * 128 + ((ch ^ (row & 7)) << 3)]);
  }

  f32x4 acc[8];
  auto compute = [&]() {
    #pragma unroll
    for (int mf = 0; mf < 8; ++mf) acc[mf] = (f32x4){0.f, 0.f, 0.f, 0.f};
    #pragma unroll
    for (int ks = 0; ks < 4; ++ks) {
      int ch = ks * 4 + (lane >> 4);
      short8 wf[8];
      #pragma unroll
      for (int mf = 0; mf < 8; ++mf) {
        int wc = mf * 16 + (lane & 15);
        wf[mf] = *reinterpret_cast<const short8*>(&sW[wc * 128 + ((ch ^ (wc & 7)) << 3)]);
      }
      #pragma unroll
      for (int mf = 0; mf < 8; ++mf)
        acc[mf] = __builtin_amdgcn_mfma_f32_16x16x32_bf16(wf[mf], af[ks], acc[mf], 0, 0, 0);
    }
  };

  const int gr = rb + wv * 16 + (lane & 15);
  const int cbase = (lane >> 4) << 2;

  // ---- phase 0: Q ----
  compute();
  if (gr < n) {
    #pragma unroll
    for (int mf = 0; mf < 8; ++mf) {
      int c0 = mf * 16 + cbase;
      f32x4 b = *reinterpret_cast<const f32x4*>(Bl + 0 * 128 + c0);
      f32x4 v = acc[mf];
      short4v h;
      h.x = (short)f2bf(v.x + b.x); h.y = (short)f2bf(v.y + b.y);
      h.z = (short)f2bf(v.z + b.z); h.w = (short)f2bf(v.w + b.w);
      *reinterpret_cast<short4v*>(Qb + (size_t)gr * HID + c0) = h;
    }
  }

  // ---- phase 1: S (fp32) ----
  __syncthreads();
  stageW(3);
  __syncthreads();
  compute();
  if (gr < n) {
    #pragma unroll
    for (int mf = 0; mf < 8; ++mf) {
      int c0 = mf * 16 + cbase;
      f32x4 b = *reinterpret_cast<const f32x4*>(Bl + 3 * 128 + c0);
      f32x4 v = acc[mf];
      v.x += b.x; v.y += b.y; v.z += b.z; v.w += b.w;
      *reinterpret_cast<f32x4*>(Sb + (size_t)gr * HID + c0) = v;
    }
  }

  // ---- phase 2: K (held in registers) ----
  __syncthreads();
  stageW(1);
  __syncthreads();
  compute();
  f32x4 kacc[8];
  #pragma unroll
  for (int mf = 0; mf < 8; ++mf) kacc[mf] = acc[mf];

  // ---- phase 3: V, store interleaved KV ----
  __syncthreads();
  stageW(2);
  __syncthreads();
  compute();
  if (gr < n) {
    #pragma unroll
    for (int mf = 0; mf < 8; ++mf) {
      int c0 = mf * 16 + cbase;
      f32x4 bk = *reinterpret_cast<const f32x4*>(Bl + 1 * 128 + c0);
      f32x4 bv = *reinterpret_cast<const f32x4*>(Bl + 2 * 128 + c0);
      f32x4 kv = kacc[mf], vv = acc[mf];
      short8 h;
      h[0] = (short)f2bf(kv.x + bk.x); h[1] = (short)f2bf(kv.y + bk.y);
      h[2] = (short)f2bf(vv.x + bv.x); h[3] = (short)f2bf(vv.y + bv.y);
      h[4] = (short)f2bf(kv.z + bk.z); h[5] = (short)f2bf(kv.w + bk.w);
      h[6] = (short)f2bf(vv.z + bv.z); h[7] = (short)f2bf(vv.w + bv.w);
      *reinterpret_cast<short8*>(KVb + (size_t)gr * 256 + 2 * c0) = h;
    }
  }
}

// ---------------- fused attention + skip + relu ----------------
// exp2-scale online softmax with deferred rescale (T13, THR=11.5 log2-units)
__global__ __launch_bounds__(256) void k_attn2(
    const unsigned short* __restrict__ Qb, const unsigned short* __restrict__ KVb,
    const float* __restrict__ Sb, const int* __restrict__ rowptr,
    const int* __restrict__ csrc, unsigned short* __restrict__ Hout, int n)
{
  int wid = blockIdx.x * 4 + (threadIdx.x >> 6);
  if (wid >= n) return;
  int lane = threadIdx.x & 63;
  ushort2v qv = *reinterpret_cast<const ushort2v*>(Qb + (size_t)wid * HID + 2 * lane);
  const float sc = 0.25503487f;  // (1/sqrt(32)) * log2(e)
  float q0 = bf2f(qv.x) * sc, q1 = bf2f(qv.y) * sc;
  int e0 = rowptr[wid], deg = rowptr[wid + 1] - e0;
  const int* cp = csrc + e0;
  const char* kvb = (const char*)KVb;
  float m = -INFINITY, s = 0.f, a0 = 0.f, a1 = 0.f;

  auto LD = [&](int i) -> ushort4v {
    return *reinterpret_cast<const ushort4v*>(kvb + (unsigned)cp[i] + lane * 8);
  };
  auto proc = [&](ushort4v kv) {
    float d = q0 * bf2f(kv.x) + q1 * bf2f(kv.y);
    float lg = dpp_rsum16(d);
    if (!__all(lg <= m + 11.5f)) {     // rare: rescale (wave-uniform branch)
      float nm = fmaxf(m, lg);
      float cc = __builtin_amdgcn_exp2f(m - nm);
      s *= cc; a0 *= cc; a1 *= cc; m = nm;
    }
    float p = __builtin_amdgcn_exp2f(lg - m);
    s += p;
    a0 = fmaf(p, bf2f(kv.z), a0);
    a1 = fmaf(p, bf2f(kv.w), a1);
  };

  int nq = deg >> 2, r = deg & 3;
  if (nq) {
    ushort4v b0 = LD(0), b1 = LD(1), b2 = LD(2), b3 = LD(3);
    for (int q = 1; q < nq; ++q) {
      int base = q * 4;
      ushort4v n0 = LD(base), n1 = LD(base + 1), n2 = LD(base + 2), n3 = LD(base + 3);
      proc(b0); proc(b1); proc(b2); proc(b3);
      b0 = n0; b1 = n1; b2 = n2; b3 = n3;
    }
    int tb = nq * 4;
    ushort4v t0, t1, t2;
    if (r > 0) t0 = LD(tb);
    if (r > 1) t1 = LD(tb + 1);
    if (r > 2) t2 = LD(tb + 2);
    proc(b0); proc(b1); proc(b2); proc(b3);
    if (r > 0) proc(t0);
    if (r > 1) proc(t1);
    if (r > 2) proc(t2);
  } else {
    for (int i = 0; i < r; ++i) proc(LD(i));
  }

  float inv = (s > 0.f) ? 1.f / s : 0.f;
  f32x2 sv = *reinterpret_cast<const f32x2*>(Sb + (size_t)wid * HID + 2 * lane);
  ushort2v h;
  h.x = f2bf(fmaxf(a0 * inv + sv.x, 0.f));
  h.y = f2bf(fmaxf(a1 * inv + sv.y, 0.f));
  *reinterpret_cast<ushort2v*>(Hout + (size_t)wid * HID + 2 * lane) = h;
}

// ---------------- pooling (batch sorted, bf16 input) ----------------
__global__ void k_pool(const unsigned short* __restrict__ Hin, const int* __restrict__ batch,
                       float* __restrict__ psum, float* __restrict__ pcnt, int n) {
  int t = threadIdx.x;  // 128 threads, one per column
  int chunk = (n + gridDim.x - 1) / gridDim.x;
  int n0 = blockIdx.x * chunk, n1 = min(n, n0 + chunk);
  if (n0 >= n1) return;
  int curg = batch[n0];
  float acc = 0.f; int c = 0;
  for (int i = n0; i < n1; ++i) {
    int g = batch[i];
    if (g != curg) {
      atomicAdd(&psum[curg * HID + t], acc);
      if (t == 0) atomicAdd(&pcnt[curg], (float)c);
      acc = 0.f; c = 0; curg = g;
    }
    acc += bf2f(Hin[(size_t)i * HID + t]); ++c;
  }
  atomicAdd(&psum[curg * HID + t], acc);
  if (t == 0) atomicAdd(&pcnt[curg], (float)c);
}

__global__ void k_fc(const float* __restrict__ psum, const float* __restrict__ pcnt,
                     const float* __restrict__ Wfc, const float* __restrict__ bfc,
                     float* __restrict__ out) {
  __shared__ float red[2];
  int g = blockIdx.x, t = threadIdx.x;  // 128 threads
  float v = psum[g * HID + t] * Wfc[t];
  #pragma unroll
  for (int off = 32; off >= 1; off >>= 1) v += __shfl_xor(v, off);
  if ((t & 63) == 0) red[t >> 6] = v;
  __syncthreads();
  if (t == 0) out[g] = (red[0] + red[1]) / fmaxf(pcnt[g], 1.f) + bfc[0];
}

extern "C" void kernel_launch(void* const* d_in, const int* in_sizes, int n_in,
                              void* d_out, int out_size, void* d_ws, size_t ws_size,
                              hipStream_t stream)
{
  const float* x   = (const float*)d_in[0];
  const int*   ei  = (const int*)d_in[1];
  const int*   bat = (const int*)d_in[2];
  const float *Wq1 = (const float*)d_in[3],  *bq1 = (const float*)d_in[4];
  const float *Wk1 = (const float*)d_in[5],  *bk1 = (const float*)d_in[6];
  const float *Wv1 = (const float*)d_in[7],  *bv1 = (const float*)d_in[8];
  const float *Ws1 = (const float*)d_in[9],  *bs1 = (const float*)d_in[10];
  const float *Wq2 = (const float*)d_in[11], *bq2 = (const float*)d_in[12];
  const float *Wk2 = (const float*)d_in[13], *bk2 = (const float*)d_in[14];
  const float *Wv2 = (const float*)d_in[15], *bv2 = (const float*)d_in[16];
  const float *Ws2 = (const float*)d_in[17], *bs2 = (const float*)d_in[18];
  const float *Wfc = (const float*)d_in[19], *bfc = (const float*)d_in[20];
  float* out = (float*)d_out;

  const int N = in_sizes[0] / HID;
  const int E = in_sizes[1] / 2;
  const int G = 64;

  char* p = (char*)d_ws;
  auto alloc = [&](size_t bytes) -> char* { char* r = p; p += align256(bytes); return r; };
  unsigned short* Qb  = (unsigned short*)alloc((size_t)N * HID * 2);
  unsigned short* KVb = (unsigned short*)alloc((size_t)N * 256 * 2);
  float* Sb   = (float*)alloc((size_t)N * HID * 4);
  unsigned short* Hb  = (unsigned short*)alloc((size_t)N * HID * 2);
  unsigned short* H2b = (unsigned short*)alloc((size_t)N * HID * 2);
  unsigned short* Wcat = (unsigned short*)alloc((size_t)8 * 128 * 128 * 2);
  float* Bcat = (float*)alloc((size_t)8 * 128 * 4);
  int* rowptr = (int*)alloc((size_t)(N + 1) * sizeof(int));
  int* cursor = (int*)alloc((size_t)N * sizeof(int));
  int* deg    = (int*)alloc((size_t)N * sizeof(int));
  int* bsum   = (int*)alloc(4096);
  int* csrc   = (int*)alloc((size_t)E * sizeof(int));
  float* psum = (float*)alloc((size_t)G * HID * sizeof(float));
  float* pcnt = (float*)alloc((size_t)G * sizeof(float));

  const int* esrc = ei;
  const int* edst = ei + E;

  hipMemsetAsync(deg, 0, (size_t)N * sizeof(int), stream);
  hipMemsetAsync(psum, 0, (size_t)G * HID * sizeof(float), stream);
  hipMemsetAsync(pcnt, 0, (size_t)G * sizeof(float), stream);

  k_wprep<<<128, 256, 0, stream>>>(Wq1, Wk1, Wv1, Ws1, Wq2, Wk2, Wv2, Ws2,
                                   bq1, bk1, bv1, bs1, bq2, bk2, bv2, bs2, Wcat, Bcat);

  k_hist<<<512, 256, 0, stream>>>(edst, deg, E);
  int SB = (N + 511) / 512;
  k_scan_a<<<SB, 512, 0, stream>>>(deg, rowptr, bsum, N);
  k_scan_b<<<1, 512, 0, stream>>>(bsum, SB);
  k_scan_c<<<SB, 512, 0, stream>>>(rowptr, cursor, bsum, N, E);
  k_scatter<<<512, 256, 0, stream>>>(esrc, edst, cursor, csrc, E);

  int QB = (N + 63) / 64;
  // layer 1 (fp32 input)
  k_qkvs<0><<<QB, 256, 0, stream>>>(x, Wcat, Bcat, Qb, KVb, Sb, N);
  k_attn2<<<(N + 3) / 4, 256, 0, stream>>>(Qb, KVb, Sb, rowptr, csrc, Hb, N);
  // layer 2 (bf16 input)
  k_qkvs<1><<<QB, 256, 0, stream>>>(Hb, Wcat + 4 * 16384, Bcat + 512, Qb, KVb, Sb, N);
  k_attn2<<<(N + 3) / 4, 256, 0, stream>>>(Qb, KVb, Sb, rowptr, csrc, H2b, N);
  // pool + fc
  k_pool<<<1024, 128, 0, stream>>>(H2b, bat, psum, pcnt, N);
  k_fc<<<G, 128, 0, stream>>>(psum, pcnt, Wfc, bfc, out);
}

// Round 5
// 398.314 us; speedup vs baseline: 2.0895x; 1.0308x over previous
//
#include <hip/hip_runtime.h>
#include <hip/hip_bf16.h>
#include <math.h>

#define HID 128

typedef __attribute__((ext_vector_type(8))) short short8;
typedef __attribute__((ext_vector_type(4))) short short4v;
typedef __attribute__((ext_vector_type(4))) float f32x4;
typedef __attribute__((ext_vector_type(2))) float f32x2;
typedef __attribute__((ext_vector_type(4))) int int4v;
typedef __attribute__((ext_vector_type(4))) unsigned short ushort4v;
typedef __attribute__((ext_vector_type(2))) unsigned short ushort2v;

static inline size_t align256(size_t x){ return (x + 255) & ~(size_t)255; }

__device__ inline float bf2f(unsigned short h) {
  union { unsigned u; float f; } uf; uf.u = ((unsigned)h) << 16; return uf.f;
}
__device__ inline unsigned short f2bf(float f) {
  union { float f; unsigned u; } uf; uf.f = f;
  unsigned r = uf.u + 0x7fff + ((uf.u >> 16) & 1);  // RNE
  return (unsigned short)(r >> 16);
}

// sum across each 16-lane group (DPP row) — pure VALU, no LDS pipe
__device__ inline float dpp_rsum16(float x) {
  int v;
  v = __builtin_amdgcn_update_dpp(0, __float_as_int(x), 0xB1, 0xF, 0xF, true);  // quad_perm [1,0,3,2]
  x += __int_as_float(v);
  v = __builtin_amdgcn_update_dpp(0, __float_as_int(x), 0x4E, 0xF, 0xF, true);  // quad_perm [2,3,0,1]
  x += __int_as_float(v);
  v = __builtin_amdgcn_update_dpp(0, __float_as_int(x), 0x124, 0xF, 0xF, true); // row_ror:4
  x += __int_as_float(v);
  v = __builtin_amdgcn_update_dpp(0, __float_as_int(x), 0x128, 0xF, 0xF, true); // row_ror:8
  x += __int_as_float(v);
  return x;
}

// ---------------- fused: weight prep (blocks 0-127) || degree histogram (blocks 128-639) ----
__global__ __launch_bounds__(256) void k_prep(
    const float* W0, const float* W1, const float* W2, const float* W3,
    const float* W4, const float* W5, const float* W6, const float* W7,
    const float* b0, const float* b1, const float* b2, const float* b3,
    const float* b4, const float* b5, const float* b6, const float* b7,
    unsigned short* Wcat, float* Bcat,
    const int* __restrict__ edst, int* __restrict__ deg, int e)
{
  __shared__ float tl[32][33];
  if (blockIdx.x >= 128) {   // histogram part
    for (int i = (blockIdx.x - 128) * 256 + threadIdx.x; i < e; i += 512 * 256)
      atomicAdd(&deg[edst[i]], 1);
    return;
  }
  const float* Ws[8] = {W0, W1, W2, W3, W4, W5, W6, W7};
  const float* bs[8] = {b0, b1, b2, b3, b4, b5, b6, b7};
  int m = blockIdx.x >> 4, tile = blockIdx.x & 15;
  int tr = (tile >> 2) * 32, tc = (tile & 3) * 32;
  int tx = threadIdx.x & 31, ty = threadIdx.x >> 5;
  const float* Wm = Ws[m];
  #pragma unroll
  for (int r = 0; r < 32; r += 8) tl[ty + r][tx] = Wm[(tr + ty + r) * 128 + tc + tx];
  __syncthreads();
  #pragma unroll
  for (int r = 0; r < 32; r += 8)
    Wcat[m * 16384 + (tc + ty + r) * 128 + tr + tx] = f2bf(tl[tx][ty + r]);
  if (tile == 0 && threadIdx.x < 128) Bcat[m * 128 + threadIdx.x] = bs[m][threadIdx.x];
}

// ---------------- CSR scan ----------------
__global__ void k_scan_a(const int* __restrict__ deg, int* __restrict__ rowptr,
                         int* __restrict__ bsum, int n) {
  __shared__ int tmp[512];
  int t = threadIdx.x, i = blockIdx.x * 512 + t;
  int v = (i < n) ? deg[i] : 0;
  tmp[t] = v;
  __syncthreads();
  for (int off = 1; off < 512; off <<= 1) {
    int u = (t >= off) ? tmp[t - off] : 0;
    __syncthreads();
    tmp[t] += u;
    __syncthreads();
  }
  if (i < n) rowptr[i] = tmp[t] - v;
  if (t == 511) bsum[blockIdx.x] = tmp[t];
}

// fused: each block sums bsum[0..bid) itself, then applies (no separate scan_b)
__global__ void k_scan_c(int* __restrict__ rowptr, int* __restrict__ cursor,
                         const int* __restrict__ bsum, int n, int e, int nb) {
  __shared__ int sred[8];
  __shared__ int base_sh;
  int t = threadIdx.x;
  int v = (t < nb && t < (int)blockIdx.x) ? bsum[t] : 0;
  #pragma unroll
  for (int off = 32; off >= 1; off >>= 1) v += __shfl_xor(v, off);
  if ((t & 63) == 0) sred[t >> 6] = v;
  __syncthreads();
  if (t == 0) {
    int b = 0;
    #pragma unroll
    for (int j = 0; j < 8; ++j) b += sred[j];
    base_sh = b;
  }
  __syncthreads();
  int base = base_sh;
  int i = blockIdx.x * 512 + t;
  if (i < n) { int val = rowptr[i] + base; rowptr[i] = val; cursor[i] = val; }
  if (i == 0) rowptr[n] = e;
}

// ---------------- QKVS projection GEMM body (bf16 MFMA, 64-row tile, 4 phases) ----------------
template<int ABF16>
__device__ __forceinline__ void qkvs_body(
    int bx, const void* __restrict__ Ain, const unsigned short* __restrict__ Wl,
    const float* __restrict__ Bl, unsigned short* __restrict__ Qb,
    unsigned short* __restrict__ KVb, float* __restrict__ Sb, int n,
    unsigned short* sA, unsigned short* sW)
{
  const int tid = threadIdx.x;
  const int rb = bx * 64;

  if (ABF16) {
    const unsigned short* A = (const unsigned short*)Ain;
    #pragma unroll
    for (int it = 0; it < 4; ++it) {
      int q = tid + it * 256;
      int row = q >> 4, ch = q & 15;
      int gr = rb + row;
      short8 h = {0,0,0,0,0,0,0,0};
      if (gr < n) h = *reinterpret_cast<const short8*>(A + (size_t)gr * HID + ch * 8);
      *reinterpret_cast<short8*>(&sA[row * 128 + ((ch ^ (row & 7)) << 3)]) = h;
    }
  } else {
    const float* A = (const float*)Ain;
    #pragma unroll
    for (int it = 0; it < 8; ++it) {
      int q = tid + it * 256;
      int row = q >> 5, c4 = (q & 31) * 4;
      int gr = rb + row;
      f32x4 a = {0.f, 0.f, 0.f, 0.f};
      if (gr < n) a = *reinterpret_cast<const f32x4*>(A + (size_t)gr * HID + c4);
      short4v h;
      h.x = (short)f2bf(a.x); h.y = (short)f2bf(a.y);
      h.z = (short)f2bf(a.z); h.w = (short)f2bf(a.w);
      int eloff = row * 128 + (((c4 >> 3) ^ (row & 7)) << 3) + (c4 & 7);
      *reinterpret_cast<short4v*>(&sA[eloff]) = h;
    }
  }

  const int lane = tid & 63;
  const int wv = tid >> 6;

  auto stageW = [&](int y) {
    const unsigned short* Wy = Wl + (size_t)y * 16384;
    #pragma unroll
    for (int it = 0; it < 8; ++it) {
      int q = tid + it * 256;
      int c = q >> 4, ch = q & 15;
      short8 w = *reinterpret_cast<const short8*>(Wy + c * 128 + ch * 8);
      *reinterpret_cast<short8*>(&sW[c * 128 + ((ch ^ (c & 7)) << 3)]) = w;
    }
  };

  stageW(0);
  __syncthreads();

  short8 af[4];
  #pragma unroll
  for (int ks = 0; ks < 4; ++ks) {
    int ch = ks * 4 + (lane >> 4);
    int row = wv * 16 + (lane & 15);
    af[ks] = *reinterpret_cast<const short8*>(&sA[row * 128 + ((ch ^ (row & 7)) << 3)]);
  }

  f32x4 acc[8];
  auto compute = [&]() {
    #pragma unroll
    for (int mf = 0; mf < 8; ++mf) acc[mf] = (f32x4){0.f, 0.f, 0.f, 0.f};
    #pragma unroll
    for (int ks = 0; ks < 4; ++ks) {
      int ch = ks * 4 + (lane >> 4);
      short8 wf[8];
      #pragma unroll
      for (int mf = 0; mf < 8; ++mf) {
        int wc = mf * 16 + (lane & 15);
        wf[mf] = *reinterpret_cast<const short8*>(&sW[wc * 128 + ((ch ^ (wc & 7)) << 3)]);
      }
      #pragma unroll
      for (int mf = 0; mf < 8; ++mf)
        acc[mf] = __builtin_amdgcn_mfma_f32_16x16x32_bf16(wf[mf], af[ks], acc[mf], 0, 0, 0);
    }
  };

  const int gr = rb + wv * 16 + (lane & 15);
  const int cbase = (lane >> 4) << 2;

  // ---- phase 0: Q ----
  compute();
  if (gr < n) {
    #pragma unroll
    for (int mf = 0; mf < 8; ++mf) {
      int c0 = mf * 16 + cbase;
      f32x4 b = *reinterpret_cast<const f32x4*>(Bl + 0 * 128 + c0);
      f32x4 v = acc[mf];
      short4v h;
      h.x = (short)f2bf(v.x + b.x); h.y = (short)f2bf(v.y + b.y);
      h.z = (short)f2bf(v.z + b.z); h.w = (short)f2bf(v.w + b.w);
      *reinterpret_cast<short4v*>(Qb + (size_t)gr * HID + c0) = h;
    }
  }

  // ---- phase 1: S (fp32) ----
  __syncthreads();
  stageW(3);
  __syncthreads();
  compute();
  if (gr < n) {
    #pragma unroll
    for (int mf = 0; mf < 8; ++mf) {
      int c0 = mf * 16 + cbase;
      f32x4 b = *reinterpret_cast<const f32x4*>(Bl + 3 * 128 + c0);
      f32x4 v = acc[mf];
      v.x += b.x; v.y += b.y; v.z += b.z; v.w += b.w;
      *reinterpret_cast<f32x4*>(Sb + (size_t)gr * HID + c0) = v;
    }
  }

  // ---- phase 2: K (held in registers) ----
  __syncthreads();
  stageW(1);
  __syncthreads();
  compute();
  f32x4 kacc[8];
  #pragma unroll
  for (int mf = 0; mf < 8; ++mf) kacc[mf] = acc[mf];

  // ---- phase 3: V, store interleaved KV ----
  __syncthreads();
  stageW(2);
  __syncthreads();
  compute();
  if (gr < n) {
    #pragma unroll
    for (int mf = 0; mf < 8; ++mf) {
      int c0 = mf * 16 + cbase;
      f32x4 bk = *reinterpret_cast<const f32x4*>(Bl + 1 * 128 + c0);
      f32x4 bv = *reinterpret_cast<const f32x4*>(Bl + 2 * 128 + c0);
      f32x4 kv = kacc[mf], vv = acc[mf];
      short8 h;
      h[0] = (short)f2bf(kv.x + bk.x); h[1] = (short)f2bf(kv.y + bk.y);
      h[2] = (short)f2bf(vv.x + bv.x); h[3] = (short)f2bf(vv.y + bv.y);
      h[4] = (short)f2bf(kv.z + bk.z); h[5] = (short)f2bf(kv.w + bk.w);
      h[6] = (short)f2bf(vv.z + bv.z); h[7] = (short)f2bf(vv.w + bv.w);
      *reinterpret_cast<short8*>(KVb + (size_t)gr * 256 + 2 * c0) = h;
    }
  }
}

// fused: scatter (blocks 0-511) || layer-1 QKVS (blocks 512+)
__global__ __launch_bounds__(256, 2) void k_scat_qkvs1(
    const int* __restrict__ srcA, const int* __restrict__ dstA,
    int* __restrict__ cursor, int* __restrict__ csrc, int e,
    const void* __restrict__ Ain, const unsigned short* __restrict__ Wl,
    const float* __restrict__ Bl, unsigned short* __restrict__ Qb,
    unsigned short* __restrict__ KVb, float* __restrict__ Sb, int n)
{
  __shared__ unsigned short sA[64 * 128];
  __shared__ unsigned short sW[128 * 128];
  if (blockIdx.x < 512) {
    for (int i = blockIdx.x * 256 + threadIdx.x; i < e; i += 512 * 256) {
      int pos = atomicAdd(&cursor[dstA[i]], 1);
      csrc[pos] = srcA[i] << 9;   // byte offset into KVb
    }
    return;
  }
  qkvs_body<0>(blockIdx.x - 512, Ain, Wl, Bl, Qb, KVb, Sb, n, sA, sW);
}

__global__ __launch_bounds__(256, 2) void k_qkvs2(
    const void* __restrict__ Ain, const unsigned short* __restrict__ Wl,
    const float* __restrict__ Bl, unsigned short* __restrict__ Qb,
    unsigned short* __restrict__ KVb, float* __restrict__ Sb, int n)
{
  __shared__ unsigned short sA[64 * 128];
  __shared__ unsigned short sW[128 * 128];
  qkvs_body<1>(blockIdx.x, Ain, Wl, Bl, Qb, KVb, Sb, n, sA, sW);
}

// ---------------- fused attention + skip + relu ----------------
// exp2-scale online softmax, quad-batched deferred rescale (one check per 4 edges)
__global__ __launch_bounds__(256) void k_attn2(
    const unsigned short* __restrict__ Qb, const unsigned short* __restrict__ KVb,
    const float* __restrict__ Sb, const int* __restrict__ rowptr,
    const int* __restrict__ csrc, unsigned short* __restrict__ Hout, int n)
{
  int wid = blockIdx.x * 4 + (threadIdx.x >> 6);
  if (wid >= n) return;
  int lane = threadIdx.x & 63;
  ushort2v qv = *reinterpret_cast<const ushort2v*>(Qb + (size_t)wid * HID + 2 * lane);
  const float sc = 0.25503487f;  // (1/sqrt(32)) * log2(e)
  float q0 = bf2f(qv.x) * sc, q1 = bf2f(qv.y) * sc;
  int e0 = rowptr[wid], deg = rowptr[wid + 1] - e0;
  const int* cp = csrc + e0;
  const char* kvb = (const char*)KVb + lane * 8;
  float m = -INFINITY, s = 0.f, a0 = 0.f, a1 = 0.f;

  auto LDo = [&](int off) -> ushort4v {
    return *reinterpret_cast<const ushort4v*>(kvb + (unsigned)off);
  };
  auto proc1 = [&](ushort4v kv) {
    float d = q0 * bf2f(kv.x) + q1 * bf2f(kv.y);
    float lg = dpp_rsum16(d);
    if (!__all(lg <= m + 11.5f)) {
      float nm = fmaxf(m, lg);
      float cc = __builtin_amdgcn_exp2f(m - nm);
      s *= cc; a0 *= cc; a1 *= cc; m = nm;
    }
    float p = __builtin_amdgcn_exp2f(lg - m);
    s += p;
    a0 = fmaf(p, bf2f(kv.z), a0);
    a1 = fmaf(p, bf2f(kv.w), a1);
  };
  auto proc4 = [&](ushort4v e0v, ushort4v e1v, ushort4v e2v, ushort4v e3v) {
    float d0 = q0 * bf2f(e0v.x) + q1 * bf2f(e0v.y);
    float d1 = q0 * bf2f(e1v.x) + q1 * bf2f(e1v.y);
    float d2 = q0 * bf2f(e2v.x) + q1 * bf2f(e2v.y);
    float d3 = q0 * bf2f(e3v.x) + q1 * bf2f(e3v.y);
    float l0 = dpp_rsum16(d0), l1 = dpp_rsum16(d1);
    float l2 = dpp_rsum16(d2), l3 = dpp_rsum16(d3);
    float qm = fmaxf(fmaxf(l0, l1), fmaxf(l2, l3));
    if (!__all(qm <= m + 11.5f)) {       // rare, wave-uniform
      float nm = fmaxf(m, qm);
      float cc = __builtin_amdgcn_exp2f(m - nm);
      s *= cc; a0 *= cc; a1 *= cc; m = nm;
    }
    float p0 = __builtin_amdgcn_exp2f(l0 - m);
    float p1 = __builtin_amdgcn_exp2f(l1 - m);
    float p2 = __builtin_amdgcn_exp2f(l2 - m);
    float p3 = __builtin_amdgcn_exp2f(l3 - m);
    s += (p0 + p1) + (p2 + p3);
    a0 = fmaf(p3, bf2f(e3v.z), fmaf(p2, bf2f(e2v.z), fmaf(p1, bf2f(e1v.z), fmaf(p0, bf2f(e0v.z), a0))));
    a1 = fmaf(p3, bf2f(e3v.w), fmaf(p2, bf2f(e2v.w), fmaf(p1, bf2f(e1v.w), fmaf(p0, bf2f(e0v.w), a1))));
  };

  int nq = deg >> 2, r = deg & 3;
  if (nq) {
    int4v o; __builtin_memcpy(&o, cp, 16);   // 4 contiguous offsets, one dwordx4
    ushort4v b0 = LDo(o.x), b1 = LDo(o.y), b2 = LDo(o.z), b3 = LDo(o.w);
    for (int q = 1; q < nq; ++q) {
      int4v no; __builtin_memcpy(&no, cp + 4 * q, 16);
      ushort4v n0 = LDo(no.x), n1 = LDo(no.y), n2 = LDo(no.z), n3 = LDo(no.w);
      proc4(b0, b1, b2, b3);
      b0 = n0; b1 = n1; b2 = n2; b3 = n3;
    }
    proc4(b0, b1, b2, b3);
  }
  int tb = nq * 4;
  for (int i = 0; i < r; ++i) proc1(LDo(cp[tb + i]));

  float inv = (s > 0.f) ? 1.f / s : 0.f;
  f32x2 sv = *reinterpret_cast<const f32x2*>(Sb + (size_t)wid * HID + 2 * lane);
  ushort2v h;
  h.x = f2bf(fmaxf(a0 * inv + sv.x, 0.f));
  h.y = f2bf(fmaxf(a1 * inv + sv.y, 0.f));
  *reinterpret_cast<ushort2v*>(Hout + (size_t)wid * HID + 2 * lane) = h;
}

// ---------------- fused mean-pool + FC (64 blocks, one per group; zero atomics) --------
__global__ __launch_bounds__(256) void k_poolfc(
    const unsigned short* __restrict__ H, const int* __restrict__ batch,
    const float* __restrict__ Wfc, const float* __restrict__ bfc,
    float* __restrict__ out, int n)
{
  int g = blockIdx.x;
  int lo = 0, hi = n;
  while (lo < hi) { int mid = (lo + hi) >> 1; if (batch[mid] < g) lo = mid + 1; else hi = mid; }
  int start = lo;
  hi = n;
  while (lo < hi) { int mid = (lo + hi) >> 1; if (batch[mid] < g + 1) lo = mid + 1; else hi = mid; }
  int end = lo;

  int t = threadIdx.x;
  int col = t & 127, rr = t >> 7;        // 2 row-streams x 128 cols
  float a0 = 0.f, a1 = 0.f, a2 = 0.f, a3 = 0.f;
  int i = start + rr;
  for (; i + 6 < end; i += 8) {
    a0 += bf2f(H[(size_t)i * HID + col]);
    a1 += bf2f(H[(size_t)(i + 2) * HID + col]);
    a2 += bf2f(H[(size_t)(i + 4) * HID + col]);
    a3 += bf2f(H[(size_t)(i + 6) * HID + col]);
  }
  for (; i < end; i += 2) a0 += bf2f(H[(size_t)i * HID + col]);
  float v = ((a0 + a1) + (a2 + a3)) * Wfc[col];

  __shared__ float red[4];
  #pragma unroll
  for (int off = 32; off >= 1; off >>= 1) v += __shfl_xor(v, off);
  if ((t & 63) == 0) red[t >> 6] = v;
  __syncthreads();
  if (t == 0) {
    float tot = (red[0] + red[1]) + (red[2] + red[3]);
    float cnt = (float)(end - start);
    out[g] = tot / fmaxf(cnt, 1.f) + bfc[0];
  }
}

extern "C" void kernel_launch(void* const* d_in, const int* in_sizes, int n_in,
                              void* d_out, int out_size, void* d_ws, size_t ws_size,
                              hipStream_t stream)
{
  const float* x   = (const float*)d_in[0];
  const int*   ei  = (const int*)d_in[1];
  const int*   bat = (const int*)d_in[2];
  const float *Wq1 = (const float*)d_in[3],  *bq1 = (const float*)d_in[4];
  const float *Wk1 = (const float*)d_in[5],  *bk1 = (const float*)d_in[6];
  const float *Wv1 = (const float*)d_in[7],  *bv1 = (const float*)d_in[8];
  const float *Ws1 = (const float*)d_in[9],  *bs1 = (const float*)d_in[10];
  const float *Wq2 = (const float*)d_in[11], *bq2 = (const float*)d_in[12];
  const float *Wk2 = (const float*)d_in[13], *bk2 = (const float*)d_in[14];
  const float *Wv2 = (const float*)d_in[15], *bv2 = (const float*)d_in[16];
  const float *Ws2 = (const float*)d_in[17], *bs2 = (const float*)d_in[18];
  const float *Wfc = (const float*)d_in[19], *bfc = (const float*)d_in[20];
  float* out = (float*)d_out;

  const int N = in_sizes[0] / HID;
  const int E = in_sizes[1] / 2;
  const int G = 64;

  char* p = (char*)d_ws;
  auto alloc = [&](size_t bytes) -> char* { char* r = p; p += align256(bytes); return r; };
  unsigned short* Qb  = (unsigned short*)alloc((size_t)N * HID * 2);
  unsigned short* KVb = (unsigned short*)alloc((size_t)N * 256 * 2);
  float* Sb   = (float*)alloc((size_t)N * HID * 4);
  unsigned short* Hb  = (unsigned short*)alloc((size_t)N * HID * 2);
  unsigned short* H2b = (unsigned short*)alloc((size_t)N * HID * 2);
  unsigned short* Wcat = (unsigned short*)alloc((size_t)8 * 128 * 128 * 2);
  float* Bcat = (float*)alloc((size_t)8 * 128 * 4);
  int* rowptr = (int*)alloc((size_t)(N + 1) * sizeof(int));
  int* cursor = (int*)alloc((size_t)N * sizeof(int));
  int* deg    = (int*)alloc((size_t)N * sizeof(int));
  int* bsum   = (int*)alloc(4096);
  int* csrc   = (int*)alloc((size_t)E * sizeof(int));

  const int* esrc = ei;
  const int* edst = ei + E;

  hipMemsetAsync(deg, 0, (size_t)N * sizeof(int), stream);

  // wprep || hist
  k_prep<<<640, 256, 0, stream>>>(Wq1, Wk1, Wv1, Ws1, Wq2, Wk2, Wv2, Ws2,
                                  bq1, bk1, bv1, bs1, bq2, bk2, bv2, bs2,
                                  Wcat, Bcat, edst, deg, E);
  int SB = (N + 511) / 512;
  k_scan_a<<<SB, 512, 0, stream>>>(deg, rowptr, bsum, N);
  k_scan_c<<<SB, 512, 0, stream>>>(rowptr, cursor, bsum, N, E, SB);

  int QB = (N + 63) / 64;
  // scatter || layer-1 QKVS
  k_scat_qkvs1<<<512 + QB, 256, 0, stream>>>(esrc, edst, cursor, csrc, E,
                                             x, Wcat, Bcat, Qb, KVb, Sb, N);
  k_attn2<<<(N + 3) / 4, 256, 0, stream>>>(Qb, KVb, Sb, rowptr, csrc, Hb, N);
  // layer 2
  k_qkvs2<<<QB, 256, 0, stream>>>(Hb, Wcat + 4 * 16384, Bcat + 512, Qb, KVb, Sb, N);
  k_attn2<<<(N + 3) / 4, 256, 0, stream>>>(Qb, KVb, Sb, rowptr, csrc, H2b, N);
  // mean-pool + fc (no atomics, no scratch)
  k_poolfc<<<G, 256, 0, stream>>>(H2b, bat, Wfc, bfc, out, N);
}